// Round 14
// baseline (534.695 us; speedup 1.0000x reference)
//
#include <hip/hip_runtime.h>
#include <hip/hip_fp16.h>
#include <math.h>

// Decomposition:
//   t1 = lrelu(feat@W1+b1); A = t1 @ Wc + bc  where Wc=W2@Wnm_top, bc=b2@Wnm_top
//   (h is never needed: it only feeds A -> fold the two linear maps, R14)
//   a_s = A@m; bd[v] = feat[v]@qb
//   w_e = exp(lrelu(a_s[src] + c1*bit + bd[dst] + c0, 0.2))  (fp32; no max)
//   neigh[v] = (sum w_e*A[src] + swb[v]*wbit)/sw[v] + B[v] + b_nm
//   out = mlp_out(relu(neigh))
// R1: same-address atomicAdd serializes -> block reduce.
// R6: fp16 A gather.  R7/R8: CSR fill = 1 random dirty line/edge; flat fill.
// R9-R12 chronic: per-lane-column matvecs LDS-broadcast-bound; compiler never
//     keeps weight arrays in VGPRs. R13: MFMA fixed it (592->415us).
// R14: (a) algebraic fusion Wc=W2@Wnm kills k_h + 51MB hH roundtrip;
//     (b) 8B CSR recs {src,w} (2 lines/node vs 4); sw/swb via atomicAdd in
//     k_fill (k_hist-pattern contention, fine; fp16 w would overflow).

typedef _Float16 h2f __attribute__((ext_vector_type(2)));
typedef _Float16 h8  __attribute__((ext_vector_type(8)));
typedef float    f4  __attribute__((ext_vector_type(4)));

static __device__ __forceinline__ float lrelu(float x, float s) {
    return x >= 0.f ? x : s * x;
}

__global__ void k_init(int* counts, float* sw, float* swb, int n) {
    int i = blockIdx.x * blockDim.x + threadIdx.x;
    if (i < n) { counts[i] = 0; sw[i] = 0.f; swb[i] = 0.f; }
}

__global__ void k_hist(const int* dst, int* counts, int E) {
    int e = blockIdx.x * blockDim.x + threadIdx.x;
    if (e < E) atomicAdd(&counts[dst[e]], 1);
}

__global__ void k_scan_a(const int* counts, int* row_off, int* partials, int n) {
    __shared__ int sd[256];
    int t = threadIdx.x;
    int base = blockIdx.x * 1024 + t * 4;
    int v0 = (base + 0 < n) ? counts[base + 0] : 0;
    int v1 = (base + 1 < n) ? counts[base + 1] : 0;
    int v2 = (base + 2 < n) ? counts[base + 2] : 0;
    int v3 = (base + 3 < n) ? counts[base + 3] : 0;
    int s = v0 + v1 + v2 + v3;
    sd[t] = s; __syncthreads();
    for (int off = 1; off < 256; off <<= 1) {
        int x = (t >= off) ? sd[t - off] : 0;
        __syncthreads();
        sd[t] += x;
        __syncthreads();
    }
    int run = sd[t] - s;
    if (base + 0 < n) row_off[base + 0] = run; run += v0;
    if (base + 1 < n) row_off[base + 1] = run; run += v1;
    if (base + 2 < n) row_off[base + 2] = run; run += v2;
    if (base + 3 < n) row_off[base + 3] = run;
    if (t == 255) partials[blockIdx.x] = sd[255];
}
__global__ void k_scan_b(int* partials, int nb) {
    if (threadIdx.x == 0 && blockIdx.x == 0) {
        int acc = 0;
        for (int i = 0; i < nb; i++) { int x = partials[i]; partials[i] = acc; acc += x; }
    }
}
__global__ void k_scan_c(int* row_off, const int* partials, int* cursor, int n, int E) {
    int i = blockIdx.x * blockDim.x + threadIdx.x;
    if (i < n) {
        int r = row_off[i] + partials[i >> 10];
        row_off[i] = r;
        cursor[i] = r;
    }
    if (i == 0) row_off[n] = E;
}

// sc[0]=c1=wbit@m  sc[1]=c0=b_nm@m  sc[2+k]=qb[k]=Wnm[129+k]@m
__global__ void k_scalars(const float* Wnm, const float* b_nm, const float* attn, float* sc) {
    __shared__ float red[128];
    int t = threadIdx.x;
    float m = attn[t];
    red[t] = Wnm[128 * 128 + t] * m; __syncthreads();
    for (int s = 64; s > 0; s >>= 1) { if (t < s) red[t] += red[t + s]; __syncthreads(); }
    if (t == 0) sc[0] = red[0];
    __syncthreads();
    red[t] = b_nm[t] * m; __syncthreads();
    for (int s = 64; s > 0; s >>= 1) { if (t < s) red[t] += red[t + s]; __syncthreads(); }
    if (t == 0) sc[1] = red[0];
    __syncthreads();
    for (int k = 0; k < 16; k++) {
        red[t] = Wnm[(129 + k) * 128 + t] * m; __syncthreads();
        for (int s = 64; s > 0; s >>= 1) { if (t < s) red[t] += red[t + s]; __syncthreads(); }
        if (t == 0) sc[2 + k] = red[0];
        __syncthreads();
    }
}

// bd[v] = feat[v] @ qb
__global__ void k_bd(const float* __restrict__ feat, const float* __restrict__ sc,
                     float* __restrict__ bd, int n) {
    int i = blockIdx.x * blockDim.x + threadIdx.x;
    if (i >= n) return;
    const float4* fr = (const float4*)(feat + (size_t)i * 16);
    float acc = 0.f;
#pragma unroll
    for (int q = 0; q < 4; q++) {
        float4 f = fr[q];
        acc = fmaf(f.x, sc[2 + 4 * q + 0], acc);
        acc = fmaf(f.y, sc[2 + 4 * q + 1], acc);
        acc = fmaf(f.z, sc[2 + 4 * q + 2], acc);
        acc = fmaf(f.w, sc[2 + 4 * q + 3], acc);
    }
    bd[i] = acc;
}

// ---------- Wc = W2 @ Wnm_top (fp16), bc = b2 @ Wnm_top (fp32) ----------
__global__ void k_wc(const float* __restrict__ W2, const float* __restrict__ b2,
                     const float* __restrict__ Wnm,
                     __half* __restrict__ Wc, float* __restrict__ bc) {
    int idx = blockIdx.x * 256 + threadIdx.x;   // 65*128 outputs (row 64 = bias)
    if (idx >= 65 * 128) return;
    int j = idx >> 7, c = idx & 127;
    const float* row = (j < 64) ? &W2[j * 128] : b2;
    float acc = 0.f;
    for (int cp = 0; cp < 128; cp++) acc = fmaf(row[cp], Wnm[cp * 128 + c], acc);
    if (j < 64) Wc[j * 128 + c] = __float2half_rn(acc);
    else bc[c] = acc;
}

// ---------- t1(fp16) = lrelu(feat@W1 + b1, 0.1)   [N,64] ----------
__global__ void __launch_bounds__(256, 4) k_t1(const float* __restrict__ feat,
                                               const float* __restrict__ W1,
                                               const float* __restrict__ b1,
                                               __half* __restrict__ t1h, int n) {
    int col = threadIdx.x & 63;
    int rg  = threadIdx.x >> 6;
    float w[16];
#pragma unroll
    for (int k = 0; k < 16; k++) w[k] = W1[k * 64 + col];
    float b = b1[col];
    for (int i = blockIdx.x * 4 + rg; i < n; i += gridDim.x * 4) {
        const float4* fr = (const float4*)(feat + (size_t)i * 16);
        float4 f0 = fr[0], f1 = fr[1], f2 = fr[2], f3 = fr[3];
        float acc = b;
        acc = fmaf(f0.x, w[0], acc);  acc = fmaf(f0.y, w[1], acc);
        acc = fmaf(f0.z, w[2], acc);  acc = fmaf(f0.w, w[3], acc);
        acc = fmaf(f1.x, w[4], acc);  acc = fmaf(f1.y, w[5], acc);
        acc = fmaf(f1.z, w[6], acc);  acc = fmaf(f1.w, w[7], acc);
        acc = fmaf(f2.x, w[8], acc);  acc = fmaf(f2.y, w[9], acc);
        acc = fmaf(f2.z, w[10], acc); acc = fmaf(f2.w, w[11], acc);
        acc = fmaf(f3.x, w[12], acc); acc = fmaf(f3.y, w[13], acc);
        acc = fmaf(f3.z, w[14], acc); acc = fmaf(f3.w, w[15], acc);
        t1h[(size_t)i * 64 + col] = __float2half_rn(lrelu(acc, 0.1f));
    }
}

// ---------- A(fp16) = t1h @ Wc + bc ; a_s = A@m   [N,64]@[64,128], MFMA ----------
__global__ void __launch_bounds__(256) k_A(const __half* __restrict__ t1h,
                                           const __half* __restrict__ Wc,
                                           const float* __restrict__ bc,
                                           const float* __restrict__ attn,
                                           __half* __restrict__ Ah,
                                           float* __restrict__ a_s,
                                           int n, int ntiles) {
    __shared__ __half Wt[128 * 72];   // Wt[c][k], stride 72: 16B-aligned
    int t = threadIdx.x;
    for (int idx = t; idx < 64 * 128; idx += 256) {
        int k = idx >> 7, c = idx & 127;
        Wt[c * 72 + k] = Wc[idx];
    }
    __syncthreads();
    int wave = t >> 6, lane = t & 63;
    int c = lane & 15, q = lane >> 4;
    float attv[8], bcv[8];
#pragma unroll
    for (int ct = 0; ct < 8; ct++) {
        attv[ct] = attn[ct * 16 + c];
        bcv[ct]  = bc[ct * 16 + c];
    }
    for (int tile = blockIdx.x * 4 + wave; tile < ntiles; tile += gridDim.x * 4) {
        int rowbase = tile * 16;
        int rm = min(rowbase + c, n - 1);
        h8 af[2];
#pragma unroll
        for (int ks = 0; ks < 2; ks++)
            af[ks] = *(const h8*)&t1h[(size_t)rm * 64 + ks * 32 + q * 8];
        f4 acc[8];
#pragma unroll
        for (int ct = 0; ct < 8; ct++) acc[ct] = (f4)(0.f);
#pragma unroll
        for (int ct = 0; ct < 8; ct++) {
#pragma unroll
            for (int ks = 0; ks < 2; ks++) {
                h8 bf = *(const h8*)&Wt[(ct * 16 + c) * 72 + ks * 32 + q * 8];
                acc[ct] = __builtin_amdgcn_mfma_f32_16x16x32_f16(af[ks], bf, acc[ct], 0, 0, 0);
            }
        }
        int rlim = n - rowbase;
        float s0 = 0.f, s1 = 0.f, s2 = 0.f, s3 = 0.f;
#pragma unroll
        for (int ct = 0; ct < 8; ct++) {
            int col = ct * 16 + c;
            float v0 = acc[ct][0] + bcv[ct];
            float v1 = acc[ct][1] + bcv[ct];
            float v2 = acc[ct][2] + bcv[ct];
            float v3 = acc[ct][3] + bcv[ct];
            if (q * 4 + 0 < rlim) Ah[(size_t)(rowbase + q * 4 + 0) * 128 + col] = __float2half_rn(v0);
            if (q * 4 + 1 < rlim) Ah[(size_t)(rowbase + q * 4 + 1) * 128 + col] = __float2half_rn(v1);
            if (q * 4 + 2 < rlim) Ah[(size_t)(rowbase + q * 4 + 2) * 128 + col] = __float2half_rn(v2);
            if (q * 4 + 3 < rlim) Ah[(size_t)(rowbase + q * 4 + 3) * 128 + col] = __float2half_rn(v3);
            s0 = fmaf(v0, attv[ct], s0);
            s1 = fmaf(v1, attv[ct], s1);
            s2 = fmaf(v2, attv[ct], s2);
            s3 = fmaf(v3, attv[ct], s3);
        }
#pragma unroll
        for (int off = 1; off < 16; off <<= 1) {
            s0 += __shfl_xor(s0, off, 64);
            s1 += __shfl_xor(s1, off, 64);
            s2 += __shfl_xor(s2, off, 64);
            s3 += __shfl_xor(s3, off, 64);
        }
        if (c == 0) {
            if (q * 4 + 0 < rlim) a_s[rowbase + q * 4 + 0] = s0;
            if (q * 4 + 1 < rlim) a_s[rowbase + q * 4 + 1] = s1;
            if (q * 4 + 2 < rlim) a_s[rowbase + q * 4 + 2] = s2;
            if (q * 4 + 3 < rlim) a_s[rowbase + q * 4 + 3] = s3;
        }
    }
}

// ---------- fill CSR: 8B rec {src, w}; sw/swb via atomics ----------
__global__ void k_fill(const int* __restrict__ src, const int* __restrict__ dst,
                       const float* __restrict__ bit, int* __restrict__ cursor,
                       const float* __restrict__ a_s, const float* __restrict__ bd,
                       const float* __restrict__ sc, int2* __restrict__ recs,
                       float* __restrict__ sw, float* __restrict__ swb, int E) {
    int e = blockIdx.x * blockDim.x + threadIdx.x;
    if (e >= E) return;
    int s = src[e], d = dst[e];
    float bv = bit[e];
    float logit = a_s[s] + sc[0] * bv + bd[d] + sc[1];
    float w = __expf(lrelu(logit, 0.2f));
    int p = atomicAdd(&cursor[d], 1);
    recs[p] = make_int2(s, __float_as_int(w));
    atomicAdd(&sw[d], w);
    atomicAdd(&swb[d], w * bv);
}

// ---------- per-node aggregate -> h_node fp16; 64 thr, 2 ch/thread ----------
__global__ void __launch_bounds__(64, 4) k_node(const float* __restrict__ feat,
                                                const float* __restrict__ Wnm,
                                                const float* __restrict__ b_nm,
                                                const __half* __restrict__ Ah,
                                                const int* __restrict__ row_off,
                                                const int2* __restrict__ recs,
                                                const float* __restrict__ sw,
                                                const float* __restrict__ swb,
                                                __half* __restrict__ h_node) {
    int v = blockIdx.x;
    int t = threadIdx.x;
    int rs = row_off[v], re = row_off[v + 1];
    h2f* outp = (h2f*)&h_node[(size_t)v * 128 + 2 * t];
    const float4* fr = (const float4*)(feat + (size_t)v * 16);
    float fv[16];
    *(float4*)&fv[0]  = fr[0];
    *(float4*)&fv[4]  = fr[1];
    *(float4*)&fv[8]  = fr[2];
    *(float4*)&fv[12] = fr[3];
    float Bx = 0.f, By = 0.f;
#pragma unroll
    for (int k = 0; k < 16; k++) {
        float2 wr = *(const float2*)&Wnm[(129 + k) * 128 + 2 * t];
        Bx = fmaf(fv[k], wr.x, Bx);
        By = fmaf(fv[k], wr.y, By);
    }
    if (re == rs) { h2f z; z[0] = (_Float16)0.f; z[1] = (_Float16)0.f; *outp = z; return; }
    float ax = 0.f, ay = 0.f;
#pragma unroll 4
    for (int p = rs; p < re; ++p) {
        int2 rec = recs[p];
        int sv = rec.x;
        float w = __int_as_float(rec.y);
        float2 av = __half22float2(*(const __half2*)&Ah[(size_t)sv * 128 + 2 * t]);
        ax = fmaf(w, av.x, ax);
        ay = fmaf(w, av.y, ay);
    }
    float inv = 1.f / sw[v];
    float swbv = swb[v];
    float2 wb = *(const float2*)&Wnm[128 * 128 + 2 * t];
    float2 bn = *(const float2*)&b_nm[2 * t];
    float hx = fmaf(swbv * inv, wb.x, ax * inv) + Bx + bn.x;
    float hy = fmaf(swbv * inv, wb.y, ay * inv) + By + bn.y;
    h2f o; o[0] = (_Float16)fmaxf(hx, 0.f); o[1] = (_Float16)fmaxf(hy, 0.f);
    *outp = o;
}

// ---------- out = bo2 + sum_c lrelu(h_node@Wo1+bo1,0.1)[c]*Wo2[c], MFMA ----------
__global__ void __launch_bounds__(256) k_out(const __half* __restrict__ h_node,
                                             const float* __restrict__ Wo1,
                                             const float* __restrict__ bo1,
                                             const float* __restrict__ Wo2,
                                             const float* __restrict__ bo2,
                                             float* __restrict__ out,
                                             int n, int ntiles) {
    __shared__ __half Wt[128 * 136];
    int t = threadIdx.x;
    for (int idx = t; idx < 128 * 128; idx += 256) {
        int k = idx >> 7, c = idx & 127;
        Wt[c * 136 + k] = __float2half_rn(Wo1[idx]);
    }
    __syncthreads();
    int wave = t >> 6, lane = t & 63;
    int c = lane & 15, q = lane >> 4;
    float b1v[8], w2v[8];
#pragma unroll
    for (int ct = 0; ct < 8; ct++) {
        b1v[ct] = bo1[ct * 16 + c];
        w2v[ct] = Wo2[ct * 16 + c];
    }
    float bias2 = bo2[0];
    for (int tile = blockIdx.x * 4 + wave; tile < ntiles; tile += gridDim.x * 4) {
        int rowbase = tile * 16;
        int rm = min(rowbase + c, n - 1);
        h8 af[4];
#pragma unroll
        for (int ks = 0; ks < 4; ks++)
            af[ks] = *(const h8*)&h_node[(size_t)rm * 128 + ks * 32 + q * 8];
        f4 acc[8];
#pragma unroll
        for (int ct = 0; ct < 8; ct++) acc[ct] = (f4)(0.f);
#pragma unroll
        for (int ct = 0; ct < 8; ct++) {
#pragma unroll
            for (int ks = 0; ks < 4; ks++) {
                h8 bf = *(const h8*)&Wt[(ct * 16 + c) * 136 + ks * 32 + q * 8];
                acc[ct] = __builtin_amdgcn_mfma_f32_16x16x32_f16(af[ks], bf, acc[ct], 0, 0, 0);
            }
        }
        int rlim = n - rowbase;
        float s0 = 0.f, s1 = 0.f, s2 = 0.f, s3 = 0.f;
#pragma unroll
        for (int ct = 0; ct < 8; ct++) {
            s0 = fmaf(lrelu(acc[ct][0] + b1v[ct], 0.1f), w2v[ct], s0);
            s1 = fmaf(lrelu(acc[ct][1] + b1v[ct], 0.1f), w2v[ct], s1);
            s2 = fmaf(lrelu(acc[ct][2] + b1v[ct], 0.1f), w2v[ct], s2);
            s3 = fmaf(lrelu(acc[ct][3] + b1v[ct], 0.1f), w2v[ct], s3);
        }
#pragma unroll
        for (int off = 1; off < 16; off <<= 1) {
            s0 += __shfl_xor(s0, off, 64);
            s1 += __shfl_xor(s1, off, 64);
            s2 += __shfl_xor(s2, off, 64);
            s3 += __shfl_xor(s3, off, 64);
        }
        if (c == 0) {
            if (q * 4 + 0 < rlim) out[rowbase + q * 4 + 0] = bias2 + s0;
            if (q * 4 + 1 < rlim) out[rowbase + q * 4 + 1] = bias2 + s1;
            if (q * 4 + 2 < rlim) out[rowbase + q * 4 + 2] = bias2 + s2;
            if (q * 4 + 3 < rlim) out[rowbase + q * 4 + 3] = bias2 + s3;
        }
    }
}

extern "C" void kernel_launch(void* const* d_in, const int* in_sizes, int n_in,
                              void* d_out, int out_size, void* d_ws, size_t ws_size,
                              hipStream_t stream) {
    const float* feat = (const float*)d_in[0];
    const float* bit  = (const float*)d_in[1];
    const int*   src  = (const int*)d_in[2];
    const int*   dst  = (const int*)d_in[3];
    const float* W1   = (const float*)d_in[4];
    const float* b1   = (const float*)d_in[5];
    const float* W2   = (const float*)d_in[6];
    const float* b2   = (const float*)d_in[7];
    const float* Wnm  = (const float*)d_in[8];
    const float* bnm  = (const float*)d_in[9];
    const float* attn = (const float*)d_in[10];
    const float* Wo1  = (const float*)d_in[11];
    const float* bo1  = (const float*)d_in[12];
    const float* Wo2  = (const float*)d_in[13];
    const float* bo2  = (const float*)d_in[14];
    float* out = (float*)d_out;
    int n = in_sizes[0] / 16;
    int E = in_sizes[2];
    int ntiles = (n + 15) / 16;

    char* wsp = (char*)d_ws;
    size_t off = 0;
    auto alloc = [&](size_t bytes) -> void* {
        void* p = wsp + off;
        off = (off + bytes + 255) & ~(size_t)255;
        return p;
    };
    __half* Ah       = (__half*)alloc((size_t)n * 128 * 2);
    __half* h_node   = (__half*)alloc((size_t)n * 128 * 2);
    __half* t1h      = (__half*)alloc((size_t)n * 64 * 2);
    float*  a_s      = (float*)alloc((size_t)n * 4);
    float*  bd       = (float*)alloc((size_t)n * 4);
    float*  sw       = (float*)alloc((size_t)n * 4);
    float*  swb      = (float*)alloc((size_t)n * 4);
    int*    counts   = (int*)alloc((size_t)n * 4);
    int*    row_off  = (int*)alloc((size_t)(n + 1) * 4);
    int*    cursor   = (int*)alloc((size_t)n * 4);
    int*    partials = (int*)alloc(8192);
    float*  sc       = (float*)alloc(256);
    __half* Wc       = (__half*)alloc(64 * 128 * 2);
    float*  bc       = (float*)alloc(128 * 4);
    int2*   recs     = (int2*)alloc((size_t)E * 8);

    int nb256 = (n + 255) / 256;
    int eb256 = (E + 255) / 256;
    int nscan = (n + 1023) / 1024;

    k_init<<<nb256, 256, 0, stream>>>(counts, sw, swb, n);
    k_hist<<<eb256, 256, 0, stream>>>(dst, counts, E);
    k_scan_a<<<nscan, 256, 0, stream>>>(counts, row_off, partials, n);
    k_scan_b<<<1, 64, 0, stream>>>(partials, nscan);
    k_scan_c<<<nb256, 256, 0, stream>>>(row_off, partials, cursor, n, E);
    k_scalars<<<1, 128, 0, stream>>>(Wnm, bnm, attn, sc);
    k_wc<<<33, 256, 0, stream>>>(W2, b2, Wnm, Wc, bc);
    k_bd<<<nb256, 256, 0, stream>>>(feat, sc, bd, n);
    k_t1<<<2048, 256, 0, stream>>>(feat, W1, b1, t1h, n);
    k_A<<<1024, 256, 0, stream>>>(t1h, Wc, bc, attn, Ah, a_s, n, ntiles);
    k_fill<<<eb256, 256, 0, stream>>>(src, dst, bit, cursor, a_s, bd, sc, recs, sw, swb, E);
    k_node<<<n, 64, 0, stream>>>(feat, Wnm, bnm, Ah, row_off, recs, sw, swb, h_node);
    k_out<<<1024, 256, 0, stream>>>(h_node, Wo1, bo1, Wo2, bo2, out, n, ntiles);
}

// Round 15
// 412.945 us; speedup vs baseline: 1.2948x; 1.2948x over previous
//
#include <hip/hip_runtime.h>
#include <hip/hip_fp16.h>
#include <math.h>

// Decomposition:
//   t1 = lrelu(feat@W1+b1); A = t1 @ Wc + bc  (Wc=W2@Wnm_top, bc=b2@Wnm_top:
//   h only feeds A, so the two linear maps fold — R14 fusion, kept)
//   a_s = A@m; bd[v] = feat[v]@qb
//   w_e = exp(lrelu(a_s[src] + c1*bit + bd[dst] + c0, 0.2))  (fp32; no max)
//   neigh[v] = (sum w_e*A[src] + (sum w_e*bit)*wbit)/sum_w + B[v] + b_nm
//   out = mlp_out(relu(neigh))
// R1: same-address atomicAdd serializes -> block reduce.
// R6: fp16 A gather.
// R7/R8/R14 lesson (CSR fill): cost = #random dirty 64B lines per edge.
//     1 line/edge (16B rec, ~90us) is the floor; 3x4B recs = 2 lines (130us);
//     adding sw/swb atomicAdds = 3 lines (220us, R14 regression). -> ONE 16B
//     record {src,w,w*bit}, sums computed serially in k_node (89us, fine).
// R9-R12 chronic: per-lane-column matvecs LDS-broadcast-bound; compiler never
//     keeps weight arrays in VGPRs. R13: MFMA fixed it (592->415us).

typedef _Float16 h2f __attribute__((ext_vector_type(2)));
typedef _Float16 h8  __attribute__((ext_vector_type(8)));
typedef float    f4  __attribute__((ext_vector_type(4)));

static __device__ __forceinline__ float lrelu(float x, float s) {
    return x >= 0.f ? x : s * x;
}

__global__ void k_init(int* counts, int n) {
    int i = blockIdx.x * blockDim.x + threadIdx.x;
    if (i < n) counts[i] = 0;
}

__global__ void k_hist(const int* dst, int* counts, int E) {
    int e = blockIdx.x * blockDim.x + threadIdx.x;
    if (e < E) atomicAdd(&counts[dst[e]], 1);
}

__global__ void k_scan_a(const int* counts, int* row_off, int* partials, int n) {
    __shared__ int sd[256];
    int t = threadIdx.x;
    int base = blockIdx.x * 1024 + t * 4;
    int v0 = (base + 0 < n) ? counts[base + 0] : 0;
    int v1 = (base + 1 < n) ? counts[base + 1] : 0;
    int v2 = (base + 2 < n) ? counts[base + 2] : 0;
    int v3 = (base + 3 < n) ? counts[base + 3] : 0;
    int s = v0 + v1 + v2 + v3;
    sd[t] = s; __syncthreads();
    for (int off = 1; off < 256; off <<= 1) {
        int x = (t >= off) ? sd[t - off] : 0;
        __syncthreads();
        sd[t] += x;
        __syncthreads();
    }
    int run = sd[t] - s;
    if (base + 0 < n) row_off[base + 0] = run; run += v0;
    if (base + 1 < n) row_off[base + 1] = run; run += v1;
    if (base + 2 < n) row_off[base + 2] = run; run += v2;
    if (base + 3 < n) row_off[base + 3] = run;
    if (t == 255) partials[blockIdx.x] = sd[255];
}
__global__ void k_scan_b(int* partials, int nb) {
    if (threadIdx.x == 0 && blockIdx.x == 0) {
        int acc = 0;
        for (int i = 0; i < nb; i++) { int x = partials[i]; partials[i] = acc; acc += x; }
    }
}
__global__ void k_scan_c(int* row_off, const int* partials, int* cursor, int n, int E) {
    int i = blockIdx.x * blockDim.x + threadIdx.x;
    if (i < n) {
        int r = row_off[i] + partials[i >> 10];
        row_off[i] = r;
        cursor[i] = r;
    }
    if (i == 0) row_off[n] = E;
}

// sc[0]=c1=wbit@m  sc[1]=c0=b_nm@m  sc[2+k]=qb[k]=Wnm[129+k]@m
__global__ void k_scalars(const float* Wnm, const float* b_nm, const float* attn, float* sc) {
    __shared__ float red[128];
    int t = threadIdx.x;
    float m = attn[t];
    red[t] = Wnm[128 * 128 + t] * m; __syncthreads();
    for (int s = 64; s > 0; s >>= 1) { if (t < s) red[t] += red[t + s]; __syncthreads(); }
    if (t == 0) sc[0] = red[0];
    __syncthreads();
    red[t] = b_nm[t] * m; __syncthreads();
    for (int s = 64; s > 0; s >>= 1) { if (t < s) red[t] += red[t + s]; __syncthreads(); }
    if (t == 0) sc[1] = red[0];
    __syncthreads();
    for (int k = 0; k < 16; k++) {
        red[t] = Wnm[(129 + k) * 128 + t] * m; __syncthreads();
        for (int s = 64; s > 0; s >>= 1) { if (t < s) red[t] += red[t + s]; __syncthreads(); }
        if (t == 0) sc[2 + k] = red[0];
        __syncthreads();
    }
}

// bd[v] = feat[v] @ qb
__global__ void k_bd(const float* __restrict__ feat, const float* __restrict__ sc,
                     float* __restrict__ bd, int n) {
    int i = blockIdx.x * blockDim.x + threadIdx.x;
    if (i >= n) return;
    const float4* fr = (const float4*)(feat + (size_t)i * 16);
    float acc = 0.f;
#pragma unroll
    for (int q = 0; q < 4; q++) {
        float4 f = fr[q];
        acc = fmaf(f.x, sc[2 + 4 * q + 0], acc);
        acc = fmaf(f.y, sc[2 + 4 * q + 1], acc);
        acc = fmaf(f.z, sc[2 + 4 * q + 2], acc);
        acc = fmaf(f.w, sc[2 + 4 * q + 3], acc);
    }
    bd[i] = acc;
}

// ---------- Wc = W2 @ Wnm_top (fp16), bc = b2 @ Wnm_top (fp32) ----------
__global__ void k_wc(const float* __restrict__ W2, const float* __restrict__ b2,
                     const float* __restrict__ Wnm,
                     __half* __restrict__ Wc, float* __restrict__ bc) {
    int idx = blockIdx.x * 256 + threadIdx.x;   // 65*128 outputs (row 64 = bias)
    if (idx >= 65 * 128) return;
    int j = idx >> 7, c = idx & 127;
    const float* row = (j < 64) ? &W2[j * 128] : b2;
    float acc = 0.f;
    for (int cp = 0; cp < 128; cp++) acc = fmaf(row[cp], Wnm[cp * 128 + c], acc);
    if (j < 64) Wc[j * 128 + c] = __float2half_rn(acc);
    else bc[c] = acc;
}

// ---------- t1(fp16) = lrelu(feat@W1 + b1, 0.1)   [N,64] ----------
__global__ void __launch_bounds__(256, 4) k_t1(const float* __restrict__ feat,
                                               const float* __restrict__ W1,
                                               const float* __restrict__ b1,
                                               __half* __restrict__ t1h, int n) {
    int col = threadIdx.x & 63;
    int rg  = threadIdx.x >> 6;
    float w[16];
#pragma unroll
    for (int k = 0; k < 16; k++) w[k] = W1[k * 64 + col];
    float b = b1[col];
    for (int i = blockIdx.x * 4 + rg; i < n; i += gridDim.x * 4) {
        const float4* fr = (const float4*)(feat + (size_t)i * 16);
        float4 f0 = fr[0], f1 = fr[1], f2 = fr[2], f3 = fr[3];
        float acc = b;
        acc = fmaf(f0.x, w[0], acc);  acc = fmaf(f0.y, w[1], acc);
        acc = fmaf(f0.z, w[2], acc);  acc = fmaf(f0.w, w[3], acc);
        acc = fmaf(f1.x, w[4], acc);  acc = fmaf(f1.y, w[5], acc);
        acc = fmaf(f1.z, w[6], acc);  acc = fmaf(f1.w, w[7], acc);
        acc = fmaf(f2.x, w[8], acc);  acc = fmaf(f2.y, w[9], acc);
        acc = fmaf(f2.z, w[10], acc); acc = fmaf(f2.w, w[11], acc);
        acc = fmaf(f3.x, w[12], acc); acc = fmaf(f3.y, w[13], acc);
        acc = fmaf(f3.z, w[14], acc); acc = fmaf(f3.w, w[15], acc);
        t1h[(size_t)i * 64 + col] = __float2half_rn(lrelu(acc, 0.1f));
    }
}

// ---------- A(fp16) = t1h @ Wc + bc ; a_s = A@m   [N,64]@[64,128], MFMA ----------
__global__ void __launch_bounds__(256) k_A(const __half* __restrict__ t1h,
                                           const __half* __restrict__ Wc,
                                           const float* __restrict__ bc,
                                           const float* __restrict__ attn,
                                           __half* __restrict__ Ah,
                                           float* __restrict__ a_s,
                                           int n, int ntiles) {
    __shared__ __half Wt[128 * 72];   // Wt[c][k], stride 72: 16B-aligned
    int t = threadIdx.x;
    for (int idx = t; idx < 64 * 128; idx += 256) {
        int k = idx >> 7, c = idx & 127;
        Wt[c * 72 + k] = Wc[idx];
    }
    __syncthreads();
    int wave = t >> 6, lane = t & 63;
    int c = lane & 15, q = lane >> 4;
    float attv[8], bcv[8];
#pragma unroll
    for (int ct = 0; ct < 8; ct++) {
        attv[ct] = attn[ct * 16 + c];
        bcv[ct]  = bc[ct * 16 + c];
    }
    for (int tile = blockIdx.x * 4 + wave; tile < ntiles; tile += gridDim.x * 4) {
        int rowbase = tile * 16;
        int rm = min(rowbase + c, n - 1);
        h8 af[2];
#pragma unroll
        for (int ks = 0; ks < 2; ks++)
            af[ks] = *(const h8*)&t1h[(size_t)rm * 64 + ks * 32 + q * 8];
        f4 acc[8];
#pragma unroll
        for (int ct = 0; ct < 8; ct++) acc[ct] = (f4)(0.f);
#pragma unroll
        for (int ct = 0; ct < 8; ct++) {
#pragma unroll
            for (int ks = 0; ks < 2; ks++) {
                h8 bf = *(const h8*)&Wt[(ct * 16 + c) * 72 + ks * 32 + q * 8];
                acc[ct] = __builtin_amdgcn_mfma_f32_16x16x32_f16(af[ks], bf, acc[ct], 0, 0, 0);
            }
        }
        int rlim = n - rowbase;
        float s0 = 0.f, s1 = 0.f, s2 = 0.f, s3 = 0.f;
#pragma unroll
        for (int ct = 0; ct < 8; ct++) {
            int col = ct * 16 + c;
            float v0 = acc[ct][0] + bcv[ct];
            float v1 = acc[ct][1] + bcv[ct];
            float v2 = acc[ct][2] + bcv[ct];
            float v3 = acc[ct][3] + bcv[ct];
            if (q * 4 + 0 < rlim) Ah[(size_t)(rowbase + q * 4 + 0) * 128 + col] = __float2half_rn(v0);
            if (q * 4 + 1 < rlim) Ah[(size_t)(rowbase + q * 4 + 1) * 128 + col] = __float2half_rn(v1);
            if (q * 4 + 2 < rlim) Ah[(size_t)(rowbase + q * 4 + 2) * 128 + col] = __float2half_rn(v2);
            if (q * 4 + 3 < rlim) Ah[(size_t)(rowbase + q * 4 + 3) * 128 + col] = __float2half_rn(v3);
            s0 = fmaf(v0, attv[ct], s0);
            s1 = fmaf(v1, attv[ct], s1);
            s2 = fmaf(v2, attv[ct], s2);
            s3 = fmaf(v3, attv[ct], s3);
        }
#pragma unroll
        for (int off = 1; off < 16; off <<= 1) {
            s0 += __shfl_xor(s0, off, 64);
            s1 += __shfl_xor(s1, off, 64);
            s2 += __shfl_xor(s2, off, 64);
            s3 += __shfl_xor(s3, off, 64);
        }
        if (c == 0) {
            if (q * 4 + 0 < rlim) a_s[rowbase + q * 4 + 0] = s0;
            if (q * 4 + 1 < rlim) a_s[rowbase + q * 4 + 1] = s1;
            if (q * 4 + 2 < rlim) a_s[rowbase + q * 4 + 2] = s2;
            if (q * 4 + 3 < rlim) a_s[rowbase + q * 4 + 3] = s3;
        }
    }
}

// ---------- fill CSR: ONE 16B record {src, w, w*bit, pad} per edge ----------
__global__ void k_fill(const int* __restrict__ src, const int* __restrict__ dst,
                       const float* __restrict__ bit, int* __restrict__ cursor,
                       const float* __restrict__ a_s, const float* __restrict__ bd,
                       const float* __restrict__ sc, float4* __restrict__ recs, int E) {
    int e = blockIdx.x * blockDim.x + threadIdx.x;
    if (e >= E) return;
    int s = src[e], d = dst[e];
    float bv = bit[e];
    float logit = a_s[s] + sc[0] * bv + bd[d] + sc[1];
    float w = __expf(lrelu(logit, 0.2f));
    int p = atomicAdd(&cursor[d], 1);
    recs[p] = make_float4(__int_as_float(s), w, w * bv, 0.f);
}

// ---------- per-node aggregate -> h_node fp16; 64 thr, 2 ch/thread ----------
__global__ void __launch_bounds__(64, 4) k_node(const float* __restrict__ feat,
                                                const float* __restrict__ Wnm,
                                                const float* __restrict__ b_nm,
                                                const __half* __restrict__ Ah,
                                                const int* __restrict__ row_off,
                                                const float4* __restrict__ recs,
                                                __half* __restrict__ h_node) {
    int v = blockIdx.x;
    int t = threadIdx.x;
    int rs = row_off[v], re = row_off[v + 1];
    h2f* outp = (h2f*)&h_node[(size_t)v * 128 + 2 * t];
    const float4* fr = (const float4*)(feat + (size_t)v * 16);
    float fv[16];
    *(float4*)&fv[0]  = fr[0];
    *(float4*)&fv[4]  = fr[1];
    *(float4*)&fv[8]  = fr[2];
    *(float4*)&fv[12] = fr[3];
    float Bx = 0.f, By = 0.f;
#pragma unroll
    for (int k = 0; k < 16; k++) {
        float2 wr = *(const float2*)&Wnm[(129 + k) * 128 + 2 * t];
        Bx = fmaf(fv[k], wr.x, Bx);
        By = fmaf(fv[k], wr.y, By);
    }
    if (re == rs) { h2f z; z[0] = (_Float16)0.f; z[1] = (_Float16)0.f; *outp = z; return; }
    float ax = 0.f, ay = 0.f, sw = 0.f, swb = 0.f;
#pragma unroll 4
    for (int p = rs; p < re; ++p) {
        float4 rec = recs[p];
        int sv = __float_as_int(rec.x);
        float2 av = __half22float2(*(const __half2*)&Ah[(size_t)sv * 128 + 2 * t]);
        ax = fmaf(rec.y, av.x, ax);
        ay = fmaf(rec.y, av.y, ay);
        sw += rec.y;
        swb += rec.z;
    }
    float inv = 1.f / sw;
    float2 wb = *(const float2*)&Wnm[128 * 128 + 2 * t];
    float2 bn = *(const float2*)&b_nm[2 * t];
    float hx = fmaf(swb * inv, wb.x, ax * inv) + Bx + bn.x;
    float hy = fmaf(swb * inv, wb.y, ay * inv) + By + bn.y;
    h2f o; o[0] = (_Float16)fmaxf(hx, 0.f); o[1] = (_Float16)fmaxf(hy, 0.f);
    *outp = o;
}

// ---------- out = bo2 + sum_c lrelu(h_node@Wo1+bo1,0.1)[c]*Wo2[c], MFMA ----------
__global__ void __launch_bounds__(256) k_out(const __half* __restrict__ h_node,
                                             const float* __restrict__ Wo1,
                                             const float* __restrict__ bo1,
                                             const float* __restrict__ Wo2,
                                             const float* __restrict__ bo2,
                                             float* __restrict__ out,
                                             int n, int ntiles) {
    __shared__ __half Wt[128 * 136];
    int t = threadIdx.x;
    for (int idx = t; idx < 128 * 128; idx += 256) {
        int k = idx >> 7, c = idx & 127;
        Wt[c * 136 + k] = __float2half_rn(Wo1[idx]);
    }
    __syncthreads();
    int wave = t >> 6, lane = t & 63;
    int c = lane & 15, q = lane >> 4;
    float b1v[8], w2v[8];
#pragma unroll
    for (int ct = 0; ct < 8; ct++) {
        b1v[ct] = bo1[ct * 16 + c];
        w2v[ct] = Wo2[ct * 16 + c];
    }
    float bias2 = bo2[0];
    for (int tile = blockIdx.x * 4 + wave; tile < ntiles; tile += gridDim.x * 4) {
        int rowbase = tile * 16;
        int rm = min(rowbase + c, n - 1);
        h8 af[4];
#pragma unroll
        for (int ks = 0; ks < 4; ks++)
            af[ks] = *(const h8*)&h_node[(size_t)rm * 128 + ks * 32 + q * 8];
        f4 acc[8];
#pragma unroll
        for (int ct = 0; ct < 8; ct++) acc[ct] = (f4)(0.f);
#pragma unroll
        for (int ct = 0; ct < 8; ct++) {
#pragma unroll
            for (int ks = 0; ks < 4; ks++) {
                h8 bf = *(const h8*)&Wt[(ct * 16 + c) * 136 + ks * 32 + q * 8];
                acc[ct] = __builtin_amdgcn_mfma_f32_16x16x32_f16(af[ks], bf, acc[ct], 0, 0, 0);
            }
        }
        int rlim = n - rowbase;
        float s0 = 0.f, s1 = 0.f, s2 = 0.f, s3 = 0.f;
#pragma unroll
        for (int ct = 0; ct < 8; ct++) {
            s0 = fmaf(lrelu(acc[ct][0] + b1v[ct], 0.1f), w2v[ct], s0);
            s1 = fmaf(lrelu(acc[ct][1] + b1v[ct], 0.1f), w2v[ct], s1);
            s2 = fmaf(lrelu(acc[ct][2] + b1v[ct], 0.1f), w2v[ct], s2);
            s3 = fmaf(lrelu(acc[ct][3] + b1v[ct], 0.1f), w2v[ct], s3);
        }
#pragma unroll
        for (int off = 1; off < 16; off <<= 1) {
            s0 += __shfl_xor(s0, off, 64);
            s1 += __shfl_xor(s1, off, 64);
            s2 += __shfl_xor(s2, off, 64);
            s3 += __shfl_xor(s3, off, 64);
        }
        if (c == 0) {
            if (q * 4 + 0 < rlim) out[rowbase + q * 4 + 0] = bias2 + s0;
            if (q * 4 + 1 < rlim) out[rowbase + q * 4 + 1] = bias2 + s1;
            if (q * 4 + 2 < rlim) out[rowbase + q * 4 + 2] = bias2 + s2;
            if (q * 4 + 3 < rlim) out[rowbase + q * 4 + 3] = bias2 + s3;
        }
    }
}

extern "C" void kernel_launch(void* const* d_in, const int* in_sizes, int n_in,
                              void* d_out, int out_size, void* d_ws, size_t ws_size,
                              hipStream_t stream) {
    const float* feat = (const float*)d_in[0];
    const float* bit  = (const float*)d_in[1];
    const int*   src  = (const int*)d_in[2];
    const int*   dst  = (const int*)d_in[3];
    const float* W1   = (const float*)d_in[4];
    const float* b1   = (const float*)d_in[5];
    const float* W2   = (const float*)d_in[6];
    const float* b2   = (const float*)d_in[7];
    const float* Wnm  = (const float*)d_in[8];
    const float* bnm  = (const float*)d_in[9];
    const float* attn = (const float*)d_in[10];
    const float* Wo1  = (const float*)d_in[11];
    const float* bo1  = (const float*)d_in[12];
    const float* Wo2  = (const float*)d_in[13];
    const float* bo2  = (const float*)d_in[14];
    float* out = (float*)d_out;
    int n = in_sizes[0] / 16;
    int E = in_sizes[2];
    int ntiles = (n + 15) / 16;

    char* wsp = (char*)d_ws;
    size_t off = 0;
    auto alloc = [&](size_t bytes) -> void* {
        void* p = wsp + off;
        off = (off + bytes + 255) & ~(size_t)255;
        return p;
    };
    __half* Ah       = (__half*)alloc((size_t)n * 128 * 2);
    __half* h_node   = (__half*)alloc((size_t)n * 128 * 2);
    __half* t1h      = (__half*)alloc((size_t)n * 64 * 2);
    float*  a_s      = (float*)alloc((size_t)n * 4);
    float*  bd       = (float*)alloc((size_t)n * 4);
    int*    counts   = (int*)alloc((size_t)n * 4);
    int*    row_off  = (int*)alloc((size_t)(n + 1) * 4);
    int*    cursor   = (int*)alloc((size_t)n * 4);
    int*    partials = (int*)alloc(8192);
    float*  sc       = (float*)alloc(256);
    __half* Wc       = (__half*)alloc(64 * 128 * 2);
    float*  bc       = (float*)alloc(128 * 4);
    float4* recs     = (float4*)alloc((size_t)E * 16);

    int nb256 = (n + 255) / 256;
    int eb256 = (E + 255) / 256;
    int nscan = (n + 1023) / 1024;

    k_init<<<nb256, 256, 0, stream>>>(counts, n);
    k_hist<<<eb256, 256, 0, stream>>>(dst, counts, E);
    k_scan_a<<<nscan, 256, 0, stream>>>(counts, row_off, partials, n);
    k_scan_b<<<1, 64, 0, stream>>>(partials, nscan);
    k_scan_c<<<nb256, 256, 0, stream>>>(row_off, partials, cursor, n, E);
    k_scalars<<<1, 128, 0, stream>>>(Wnm, bnm, attn, sc);
    k_wc<<<33, 256, 0, stream>>>(W2, b2, Wnm, Wc, bc);
    k_bd<<<nb256, 256, 0, stream>>>(feat, sc, bd, n);
    k_t1<<<2048, 256, 0, stream>>>(feat, W1, b1, t1h, n);
    k_A<<<1024, 256, 0, stream>>>(t1h, Wc, bc, attn, Ah, a_s, n, ntiles);
    k_fill<<<eb256, 256, 0, stream>>>(src, dst, bit, cursor, a_s, bd, sc, recs, E);
    k_node<<<n, 64, 0, stream>>>(feat, Wnm, bnm, Ah, row_off, recs, h_node);
    k_out<<<1024, 256, 0, stream>>>(h_node, Wo1, bo1, Wo2, bo2, out, n, ntiles);
}

// Round 16
// 406.608 us; speedup vs baseline: 1.3150x; 1.0156x over previous
//
#include <hip/hip_runtime.h>
#include <hip/hip_fp16.h>
#include <math.h>

// Decomposition:
//   t1 = lrelu(feat@W1+b1); A = t1 @ Wc + bc  (Wc=W2@Wnm_top: h only feeds A)
//   a_s = A@m; bd[v] = feat[v]@qb
//   w_e = exp(lrelu(a_s[src] + c1*bit + bd[dst] + c0, 0.2))  (fp32; no max)
//   neigh[v] = (sum w_e*A[src] + (sum w_e*bit)*wbit)/sum_w + B[v] + b_nm
//   out = mlp_out(relu(neigh))
// R1: same-address atomicAdd serializes -> block reduce.
// R6: fp16 A gather.
// R7/R8/R14: CSR fill cost = #random dirty 64B lines/edge; 1 line (16B rec) is
//     the flat floor; extra atomics or finer recs only add lines.
// R13: MFMA for the dense matvecs (LDS-broadcast + weight-residency escape).
// R15 counters: k_fill WRITE=102MB for a 25.6MB recs array = 4x amplification
//     (4 recs/line arrive from different XCDs; each partial line written back).
// R16: XCD-local fill — 8 dst-slices, slice j handled by blocks blockIdx&7==j
//     (round-robin XCD heuristic); write window 3.2MB < 4MB L2/XCD so lines
//     accumulate in ONE L2 and write back once. Costs 8x edge-stream re-scan
//     (154MB seq ~ 25us). If WRITE_SIZE stays ~100MB the heuristic failed.

typedef _Float16 h2f __attribute__((ext_vector_type(2)));
typedef _Float16 h8  __attribute__((ext_vector_type(8)));
typedef float    f4  __attribute__((ext_vector_type(4)));

static __device__ __forceinline__ float lrelu(float x, float s) {
    return x >= 0.f ? x : s * x;
}

__global__ void k_init(int* counts, int n) {
    int i = blockIdx.x * blockDim.x + threadIdx.x;
    if (i < n) counts[i] = 0;
}

__global__ void k_hist(const int* dst, int* counts, int E) {
    int e = blockIdx.x * blockDim.x + threadIdx.x;
    if (e < E) atomicAdd(&counts[dst[e]], 1);
}

__global__ void k_scan_a(const int* counts, int* row_off, int* partials, int n) {
    __shared__ int sd[256];
    int t = threadIdx.x;
    int base = blockIdx.x * 1024 + t * 4;
    int v0 = (base + 0 < n) ? counts[base + 0] : 0;
    int v1 = (base + 1 < n) ? counts[base + 1] : 0;
    int v2 = (base + 2 < n) ? counts[base + 2] : 0;
    int v3 = (base + 3 < n) ? counts[base + 3] : 0;
    int s = v0 + v1 + v2 + v3;
    sd[t] = s; __syncthreads();
    for (int off = 1; off < 256; off <<= 1) {
        int x = (t >= off) ? sd[t - off] : 0;
        __syncthreads();
        sd[t] += x;
        __syncthreads();
    }
    int run = sd[t] - s;
    if (base + 0 < n) row_off[base + 0] = run; run += v0;
    if (base + 1 < n) row_off[base + 1] = run; run += v1;
    if (base + 2 < n) row_off[base + 2] = run; run += v2;
    if (base + 3 < n) row_off[base + 3] = run;
    if (t == 255) partials[blockIdx.x] = sd[255];
}
__global__ void k_scan_b(int* partials, int nb) {
    if (threadIdx.x == 0 && blockIdx.x == 0) {
        int acc = 0;
        for (int i = 0; i < nb; i++) { int x = partials[i]; partials[i] = acc; acc += x; }
    }
}
__global__ void k_scan_c(int* row_off, const int* partials, int* cursor, int n, int E) {
    int i = blockIdx.x * blockDim.x + threadIdx.x;
    if (i < n) {
        int r = row_off[i] + partials[i >> 10];
        row_off[i] = r;
        cursor[i] = r;
    }
    if (i == 0) row_off[n] = E;
}

// sc[0]=c1=wbit@m  sc[1]=c0=b_nm@m  sc[2+k]=qb[k]=Wnm[129+k]@m
__global__ void k_scalars(const float* Wnm, const float* b_nm, const float* attn, float* sc) {
    __shared__ float red[128];
    int t = threadIdx.x;
    float m = attn[t];
    red[t] = Wnm[128 * 128 + t] * m; __syncthreads();
    for (int s = 64; s > 0; s >>= 1) { if (t < s) red[t] += red[t + s]; __syncthreads(); }
    if (t == 0) sc[0] = red[0];
    __syncthreads();
    red[t] = b_nm[t] * m; __syncthreads();
    for (int s = 64; s > 0; s >>= 1) { if (t < s) red[t] += red[t + s]; __syncthreads(); }
    if (t == 0) sc[1] = red[0];
    __syncthreads();
    for (int k = 0; k < 16; k++) {
        red[t] = Wnm[(129 + k) * 128 + t] * m; __syncthreads();
        for (int s = 64; s > 0; s >>= 1) { if (t < s) red[t] += red[t + s]; __syncthreads(); }
        if (t == 0) sc[2 + k] = red[0];
        __syncthreads();
    }
}

// bd[v] = feat[v] @ qb
__global__ void k_bd(const float* __restrict__ feat, const float* __restrict__ sc,
                     float* __restrict__ bd, int n) {
    int i = blockIdx.x * blockDim.x + threadIdx.x;
    if (i >= n) return;
    const float4* fr = (const float4*)(feat + (size_t)i * 16);
    float acc = 0.f;
#pragma unroll
    for (int q = 0; q < 4; q++) {
        float4 f = fr[q];
        acc = fmaf(f.x, sc[2 + 4 * q + 0], acc);
        acc = fmaf(f.y, sc[2 + 4 * q + 1], acc);
        acc = fmaf(f.z, sc[2 + 4 * q + 2], acc);
        acc = fmaf(f.w, sc[2 + 4 * q + 3], acc);
    }
    bd[i] = acc;
}

// ---------- Wc = W2 @ Wnm_top (fp16), bc = b2 @ Wnm_top (fp32) ----------
__global__ void k_wc(const float* __restrict__ W2, const float* __restrict__ b2,
                     const float* __restrict__ Wnm,
                     __half* __restrict__ Wc, float* __restrict__ bc) {
    int idx = blockIdx.x * 256 + threadIdx.x;   // 65*128 outputs (row 64 = bias)
    if (idx >= 65 * 128) return;
    int j = idx >> 7, c = idx & 127;
    const float* row = (j < 64) ? &W2[j * 128] : b2;
    float acc = 0.f;
    for (int cp = 0; cp < 128; cp++) acc = fmaf(row[cp], Wnm[cp * 128 + c], acc);
    if (j < 64) Wc[j * 128 + c] = __float2half_rn(acc);
    else bc[c] = acc;
}

// ---------- t1(fp16) = lrelu(feat@W1 + b1, 0.1)   [N,64] ----------
__global__ void __launch_bounds__(256, 4) k_t1(const float* __restrict__ feat,
                                               const float* __restrict__ W1,
                                               const float* __restrict__ b1,
                                               __half* __restrict__ t1h, int n) {
    int col = threadIdx.x & 63;
    int rg  = threadIdx.x >> 6;
    float w[16];
#pragma unroll
    for (int k = 0; k < 16; k++) w[k] = W1[k * 64 + col];
    float b = b1[col];
    for (int i = blockIdx.x * 4 + rg; i < n; i += gridDim.x * 4) {
        const float4* fr = (const float4*)(feat + (size_t)i * 16);
        float4 f0 = fr[0], f1 = fr[1], f2 = fr[2], f3 = fr[3];
        float acc = b;
        acc = fmaf(f0.x, w[0], acc);  acc = fmaf(f0.y, w[1], acc);
        acc = fmaf(f0.z, w[2], acc);  acc = fmaf(f0.w, w[3], acc);
        acc = fmaf(f1.x, w[4], acc);  acc = fmaf(f1.y, w[5], acc);
        acc = fmaf(f1.z, w[6], acc);  acc = fmaf(f1.w, w[7], acc);
        acc = fmaf(f2.x, w[8], acc);  acc = fmaf(f2.y, w[9], acc);
        acc = fmaf(f2.z, w[10], acc); acc = fmaf(f2.w, w[11], acc);
        acc = fmaf(f3.x, w[12], acc); acc = fmaf(f3.y, w[13], acc);
        acc = fmaf(f3.z, w[14], acc); acc = fmaf(f3.w, w[15], acc);
        t1h[(size_t)i * 64 + col] = __float2half_rn(lrelu(acc, 0.1f));
    }
}

// ---------- A(fp16) = t1h @ Wc + bc ; a_s = A@m   [N,64]@[64,128], MFMA ----------
__global__ void __launch_bounds__(256) k_A(const __half* __restrict__ t1h,
                                           const __half* __restrict__ Wc,
                                           const float* __restrict__ bc,
                                           const float* __restrict__ attn,
                                           __half* __restrict__ Ah,
                                           float* __restrict__ a_s,
                                           int n, int ntiles) {
    __shared__ __half Wt[128 * 72];   // Wt[c][k], stride 72: 16B-aligned
    int t = threadIdx.x;
    for (int idx = t; idx < 64 * 128; idx += 256) {
        int k = idx >> 7, c = idx & 127;
        Wt[c * 72 + k] = Wc[idx];
    }
    __syncthreads();
    int wave = t >> 6, lane = t & 63;
    int c = lane & 15, q = lane >> 4;
    float attv[8], bcv[8];
#pragma unroll
    for (int ct = 0; ct < 8; ct++) {
        attv[ct] = attn[ct * 16 + c];
        bcv[ct]  = bc[ct * 16 + c];
    }
    for (int tile = blockIdx.x * 4 + wave; tile < ntiles; tile += gridDim.x * 4) {
        int rowbase = tile * 16;
        int rm = min(rowbase + c, n - 1);
        h8 af[2];
#pragma unroll
        for (int ks = 0; ks < 2; ks++)
            af[ks] = *(const h8*)&t1h[(size_t)rm * 64 + ks * 32 + q * 8];
        f4 acc[8];
#pragma unroll
        for (int ct = 0; ct < 8; ct++) acc[ct] = (f4)(0.f);
#pragma unroll
        for (int ct = 0; ct < 8; ct++) {
#pragma unroll
            for (int ks = 0; ks < 2; ks++) {
                h8 bf = *(const h8*)&Wt[(ct * 16 + c) * 72 + ks * 32 + q * 8];
                acc[ct] = __builtin_amdgcn_mfma_f32_16x16x32_f16(af[ks], bf, acc[ct], 0, 0, 0);
            }
        }
        int rlim = n - rowbase;
        float s0 = 0.f, s1 = 0.f, s2 = 0.f, s3 = 0.f;
#pragma unroll
        for (int ct = 0; ct < 8; ct++) {
            int col = ct * 16 + c;
            float v0 = acc[ct][0] + bcv[ct];
            float v1 = acc[ct][1] + bcv[ct];
            float v2 = acc[ct][2] + bcv[ct];
            float v3 = acc[ct][3] + bcv[ct];
            if (q * 4 + 0 < rlim) Ah[(size_t)(rowbase + q * 4 + 0) * 128 + col] = __float2half_rn(v0);
            if (q * 4 + 1 < rlim) Ah[(size_t)(rowbase + q * 4 + 1) * 128 + col] = __float2half_rn(v1);
            if (q * 4 + 2 < rlim) Ah[(size_t)(rowbase + q * 4 + 2) * 128 + col] = __float2half_rn(v2);
            if (q * 4 + 3 < rlim) Ah[(size_t)(rowbase + q * 4 + 3) * 128 + col] = __float2half_rn(v3);
            s0 = fmaf(v0, attv[ct], s0);
            s1 = fmaf(v1, attv[ct], s1);
            s2 = fmaf(v2, attv[ct], s2);
            s3 = fmaf(v3, attv[ct], s3);
        }
#pragma unroll
        for (int off = 1; off < 16; off <<= 1) {
            s0 += __shfl_xor(s0, off, 64);
            s1 += __shfl_xor(s1, off, 64);
            s2 += __shfl_xor(s2, off, 64);
            s3 += __shfl_xor(s3, off, 64);
        }
        if (c == 0) {
            if (q * 4 + 0 < rlim) a_s[rowbase + q * 4 + 0] = s0;
            if (q * 4 + 1 < rlim) a_s[rowbase + q * 4 + 1] = s1;
            if (q * 4 + 2 < rlim) a_s[rowbase + q * 4 + 2] = s2;
            if (q * 4 + 3 < rlim) a_s[rowbase + q * 4 + 3] = s3;
        }
    }
}

// ---------- XCD-local fill: 8 dst-slices, slice = blockIdx&7 ----------
__global__ void __launch_bounds__(256) k_fill(const int* __restrict__ src,
                                              const int* __restrict__ dst,
                                              const float* __restrict__ bit,
                                              int* __restrict__ cursor,
                                              const float* __restrict__ a_s,
                                              const float* __restrict__ bd,
                                              const float* __restrict__ sc,
                                              float4* __restrict__ recs, int E, int n) {
    int part = blockIdx.x & 7;            // XCD heuristic: round-robin by blockIdx
    int slice = n >> 3;
    int lo = part * slice;
    int hi = (part == 7) ? n : lo + slice;
    int nb = gridDim.x >> 3;
    int bid = blockIdx.x >> 3;
    float c1 = sc[0], c0 = sc[1];
    for (int e = bid * 256 + threadIdx.x; e < E; e += nb * 256) {
        int d = dst[e];
        if (d < lo || d >= hi) continue;
        int s = src[e];
        float bv = bit[e];
        float logit = a_s[s] + c1 * bv + bd[d] + c0;
        float w = __expf(lrelu(logit, 0.2f));
        int p = atomicAdd(&cursor[d], 1);
        recs[p] = make_float4(__int_as_float(s), w, w * bv, 0.f);
    }
}

// ---------- per-node aggregate -> h_node fp16; 64 thr, 2 ch/thread ----------
__global__ void __launch_bounds__(64, 4) k_node(const float* __restrict__ feat,
                                                const float* __restrict__ Wnm,
                                                const float* __restrict__ b_nm,
                                                const __half* __restrict__ Ah,
                                                const int* __restrict__ row_off,
                                                const float4* __restrict__ recs,
                                                __half* __restrict__ h_node) {
    int v = blockIdx.x;
    int t = threadIdx.x;
    int rs = row_off[v], re = row_off[v + 1];
    h2f* outp = (h2f*)&h_node[(size_t)v * 128 + 2 * t];
    const float4* fr = (const float4*)(feat + (size_t)v * 16);
    float fv[16];
    *(float4*)&fv[0]  = fr[0];
    *(float4*)&fv[4]  = fr[1];
    *(float4*)&fv[8]  = fr[2];
    *(float4*)&fv[12] = fr[3];
    float Bx = 0.f, By = 0.f;
#pragma unroll
    for (int k = 0; k < 16; k++) {
        float2 wr = *(const float2*)&Wnm[(129 + k) * 128 + 2 * t];
        Bx = fmaf(fv[k], wr.x, Bx);
        By = fmaf(fv[k], wr.y, By);
    }
    if (re == rs) { h2f z; z[0] = (_Float16)0.f; z[1] = (_Float16)0.f; *outp = z; return; }
    float ax = 0.f, ay = 0.f, sw = 0.f, swb = 0.f;
#pragma unroll 4
    for (int p = rs; p < re; ++p) {
        float4 rec = recs[p];
        int sv = __float_as_int(rec.x);
        float2 av = __half22float2(*(const __half2*)&Ah[(size_t)sv * 128 + 2 * t]);
        ax = fmaf(rec.y, av.x, ax);
        ay = fmaf(rec.y, av.y, ay);
        sw += rec.y;
        swb += rec.z;
    }
    float inv = 1.f / sw;
    float2 wb = *(const float2*)&Wnm[128 * 128 + 2 * t];
    float2 bn = *(const float2*)&b_nm[2 * t];
    float hx = fmaf(swb * inv, wb.x, ax * inv) + Bx + bn.x;
    float hy = fmaf(swb * inv, wb.y, ay * inv) + By + bn.y;
    h2f o; o[0] = (_Float16)fmaxf(hx, 0.f); o[1] = (_Float16)fmaxf(hy, 0.f);
    *outp = o;
}

// ---------- out = bo2 + sum_c lrelu(h_node@Wo1+bo1,0.1)[c]*Wo2[c], MFMA ----------
__global__ void __launch_bounds__(256) k_out(const __half* __restrict__ h_node,
                                             const float* __restrict__ Wo1,
                                             const float* __restrict__ bo1,
                                             const float* __restrict__ Wo2,
                                             const float* __restrict__ bo2,
                                             float* __restrict__ out,
                                             int n, int ntiles) {
    __shared__ __half Wt[128 * 136];
    int t = threadIdx.x;
    for (int idx = t; idx < 128 * 128; idx += 256) {
        int k = idx >> 7, c = idx & 127;
        Wt[c * 136 + k] = __float2half_rn(Wo1[idx]);
    }
    __syncthreads();
    int wave = t >> 6, lane = t & 63;
    int c = lane & 15, q = lane >> 4;
    float b1v[8], w2v[8];
#pragma unroll
    for (int ct = 0; ct < 8; ct++) {
        b1v[ct] = bo1[ct * 16 + c];
        w2v[ct] = Wo2[ct * 16 + c];
    }
    float bias2 = bo2[0];
    for (int tile = blockIdx.x * 4 + wave; tile < ntiles; tile += gridDim.x * 4) {
        int rowbase = tile * 16;
        int rm = min(rowbase + c, n - 1);
        h8 af[4];
#pragma unroll
        for (int ks = 0; ks < 4; ks++)
            af[ks] = *(const h8*)&h_node[(size_t)rm * 128 + ks * 32 + q * 8];
        f4 acc[8];
#pragma unroll
        for (int ct = 0; ct < 8; ct++) acc[ct] = (f4)(0.f);
#pragma unroll
        for (int ct = 0; ct < 8; ct++) {
#pragma unroll
            for (int ks = 0; ks < 4; ks++) {
                h8 bf = *(const h8*)&Wt[(ct * 16 + c) * 136 + ks * 32 + q * 8];
                acc[ct] = __builtin_amdgcn_mfma_f32_16x16x32_f16(af[ks], bf, acc[ct], 0, 0, 0);
            }
        }
        int rlim = n - rowbase;
        float s0 = 0.f, s1 = 0.f, s2 = 0.f, s3 = 0.f;
#pragma unroll
        for (int ct = 0; ct < 8; ct++) {
            s0 = fmaf(lrelu(acc[ct][0] + b1v[ct], 0.1f), w2v[ct], s0);
            s1 = fmaf(lrelu(acc[ct][1] + b1v[ct], 0.1f), w2v[ct], s1);
            s2 = fmaf(lrelu(acc[ct][2] + b1v[ct], 0.1f), w2v[ct], s2);
            s3 = fmaf(lrelu(acc[ct][3] + b1v[ct], 0.1f), w2v[ct], s3);
        }
#pragma unroll
        for (int off = 1; off < 16; off <<= 1) {
            s0 += __shfl_xor(s0, off, 64);
            s1 += __shfl_xor(s1, off, 64);
            s2 += __shfl_xor(s2, off, 64);
            s3 += __shfl_xor(s3, off, 64);
        }
        if (c == 0) {
            if (q * 4 + 0 < rlim) out[rowbase + q * 4 + 0] = bias2 + s0;
            if (q * 4 + 1 < rlim) out[rowbase + q * 4 + 1] = bias2 + s1;
            if (q * 4 + 2 < rlim) out[rowbase + q * 4 + 2] = bias2 + s2;
            if (q * 4 + 3 < rlim) out[rowbase + q * 4 + 3] = bias2 + s3;
        }
    }
}

extern "C" void kernel_launch(void* const* d_in, const int* in_sizes, int n_in,
                              void* d_out, int out_size, void* d_ws, size_t ws_size,
                              hipStream_t stream) {
    const float* feat = (const float*)d_in[0];
    const float* bit  = (const float*)d_in[1];
    const int*   src  = (const int*)d_in[2];
    const int*   dst  = (const int*)d_in[3];
    const float* W1   = (const float*)d_in[4];
    const float* b1   = (const float*)d_in[5];
    const float* W2   = (const float*)d_in[6];
    const float* b2   = (const float*)d_in[7];
    const float* Wnm  = (const float*)d_in[8];
    const float* bnm  = (const float*)d_in[9];
    const float* attn = (const float*)d_in[10];
    const float* Wo1  = (const float*)d_in[11];
    const float* bo1  = (const float*)d_in[12];
    const float* Wo2  = (const float*)d_in[13];
    const float* bo2  = (const float*)d_in[14];
    float* out = (float*)d_out;
    int n = in_sizes[0] / 16;
    int E = in_sizes[2];
    int ntiles = (n + 15) / 16;

    char* wsp = (char*)d_ws;
    size_t off = 0;
    auto alloc = [&](size_t bytes) -> void* {
        void* p = wsp + off;
        off = (off + bytes + 255) & ~(size_t)255;
        return p;
    };
    __half* Ah       = (__half*)alloc((size_t)n * 128 * 2);
    __half* h_node   = (__half*)alloc((size_t)n * 128 * 2);
    __half* t1h      = (__half*)alloc((size_t)n * 64 * 2);
    float*  a_s      = (float*)alloc((size_t)n * 4);
    float*  bd       = (float*)alloc((size_t)n * 4);
    int*    counts   = (int*)alloc((size_t)n * 4);
    int*    row_off  = (int*)alloc((size_t)(n + 1) * 4);
    int*    cursor   = (int*)alloc((size_t)n * 4);
    int*    partials = (int*)alloc(8192);
    float*  sc       = (float*)alloc(256);
    __half* Wc       = (__half*)alloc(64 * 128 * 2);
    float*  bc       = (float*)alloc(128 * 4);
    float4* recs     = (float4*)alloc((size_t)E * 16);

    int nb256 = (n + 255) / 256;
    int eb256 = (E + 255) / 256;
    int nscan = (n + 1023) / 1024;

    k_init<<<nb256, 256, 0, stream>>>(counts, n);
    k_hist<<<eb256, 256, 0, stream>>>(dst, counts, E);
    k_scan_a<<<nscan, 256, 0, stream>>>(counts, row_off, partials, n);
    k_scan_b<<<1, 64, 0, stream>>>(partials, nscan);
    k_scan_c<<<nb256, 256, 0, stream>>>(row_off, partials, cursor, n, E);
    k_scalars<<<1, 128, 0, stream>>>(Wnm, bnm, attn, sc);
    k_wc<<<33, 256, 0, stream>>>(W2, b2, Wnm, Wc, bc);
    k_bd<<<nb256, 256, 0, stream>>>(feat, sc, bd, n);
    k_t1<<<2048, 256, 0, stream>>>(feat, W1, b1, t1h, n);
    k_A<<<1024, 256, 0, stream>>>(t1h, Wc, bc, attn, Ah, a_s, n, ntiles);
    k_fill<<<8 * 832, 256, 0, stream>>>(src, dst, bit, cursor, a_s, bd, sc, recs, E, n);
    k_node<<<n, 64, 0, stream>>>(feat, Wnm, bnm, Ah, row_off, recs, h_node);
    k_out<<<1024, 256, 0, stream>>>(h_node, Wo1, bo1, Wo2, bo2, out, n, ntiles);
}

// Round 17
// 392.985 us; speedup vs baseline: 1.3606x; 1.0347x over previous
//
#include <hip/hip_runtime.h>
#include <hip/hip_fp16.h>
#include <math.h>

// Decomposition:
//   t1 = lrelu(feat@W1+b1); A = t1 @ Wc + bc  (Wc=W2@Wnm_top: h only feeds A)
//   a_s = A@m; bd[v] = feat[v]@qb   (bd fused into k_t1 — R17)
//   w_e = exp(lrelu(a_s[src] + c1*bit + bd[dst] + c0, 0.2))  (fp32; no max)
//   neigh[v] = (sum w_e*A[src] + (sum w_e*bit)*wbit)/sum_w + B[v] + b_nm
//   out = mlp_out(relu(neigh))
// R1: same-address atomicAdd serializes -> block reduce.
// R6: fp16 A gather. R13: MFMA for dense matvecs.
// R7/R8/R14/R16 (CSR fill saga): cost = 1 random dirty 64B line/edge, ~92us
//     flat floor. Finer recs (2-3 lines) worse; bucket-binning (contended
//     cursors) worse; XCD-slicing didn't cut WRITE (105MB) and added 76MB
//     fetch. Flat 16B-rec fill is optimal. STOP TOUCHING IT.
// R17: consolidate the mid-tier (~225us across 11 small dispatches):
//     k_bd->k_t1 (row already in regs), k_scalars+k_wc->k_prep,
//     k_init->hipMemsetAsync, k_node unroll 8 (probe latency- vs BW-bound).

typedef _Float16 h2f __attribute__((ext_vector_type(2)));
typedef _Float16 h8  __attribute__((ext_vector_type(8)));
typedef float    f4  __attribute__((ext_vector_type(4)));

static __device__ __forceinline__ float lrelu(float x, float s) {
    return x >= 0.f ? x : s * x;
}

__global__ void k_hist(const int* dst, int* counts, int E) {
    int e = blockIdx.x * blockDim.x + threadIdx.x;
    if (e < E) atomicAdd(&counts[dst[e]], 1);
}

__global__ void k_scan_a(const int* counts, int* row_off, int* partials, int n) {
    __shared__ int sd[256];
    int t = threadIdx.x;
    int base = blockIdx.x * 1024 + t * 4;
    int v0 = (base + 0 < n) ? counts[base + 0] : 0;
    int v1 = (base + 1 < n) ? counts[base + 1] : 0;
    int v2 = (base + 2 < n) ? counts[base + 2] : 0;
    int v3 = (base + 3 < n) ? counts[base + 3] : 0;
    int s = v0 + v1 + v2 + v3;
    sd[t] = s; __syncthreads();
    for (int off = 1; off < 256; off <<= 1) {
        int x = (t >= off) ? sd[t - off] : 0;
        __syncthreads();
        sd[t] += x;
        __syncthreads();
    }
    int run = sd[t] - s;
    if (base + 0 < n) row_off[base + 0] = run; run += v0;
    if (base + 1 < n) row_off[base + 1] = run; run += v1;
    if (base + 2 < n) row_off[base + 2] = run; run += v2;
    if (base + 3 < n) row_off[base + 3] = run;
    if (t == 255) partials[blockIdx.x] = sd[255];
}
__global__ void k_scan_b(int* partials, int nb) {
    if (threadIdx.x == 0 && blockIdx.x == 0) {
        int acc = 0;
        for (int i = 0; i < nb; i++) { int x = partials[i]; partials[i] = acc; acc += x; }
    }
}
__global__ void k_scan_c(int* row_off, const int* partials, int* cursor, int n, int E) {
    int i = blockIdx.x * blockDim.x + threadIdx.x;
    if (i < n) {
        int r = row_off[i] + partials[i >> 10];
        row_off[i] = r;
        cursor[i] = r;
    }
    if (i == 0) row_off[n] = E;
}

// ---------- k_prep: block 0 -> sc[] scalars; blocks 1..33 -> Wc, bc ----------
// sc[0]=c1=wbit@m  sc[1]=c0=b_nm@m  sc[2+k]=qb[k]=Wnm[129+k]@m
__global__ void __launch_bounds__(256) k_prep(const float* __restrict__ W2,
                                              const float* __restrict__ b2,
                                              const float* __restrict__ Wnm,
                                              const float* __restrict__ b_nm,
                                              const float* __restrict__ attn,
                                              __half* __restrict__ Wc,
                                              float* __restrict__ bc,
                                              float* __restrict__ sc) {
    int t = threadIdx.x;
    if (blockIdx.x == 0) {
        __shared__ float red[128];
        float m = (t < 128) ? attn[t] : 0.f;
        if (t < 128) red[t] = Wnm[128 * 128 + t] * m;
        __syncthreads();
        for (int s = 64; s > 0; s >>= 1) { if (t < s) red[t] += red[t + s]; __syncthreads(); }
        if (t == 0) sc[0] = red[0];
        __syncthreads();
        if (t < 128) red[t] = b_nm[t] * m;
        __syncthreads();
        for (int s = 64; s > 0; s >>= 1) { if (t < s) red[t] += red[t + s]; __syncthreads(); }
        if (t == 0) sc[1] = red[0];
        __syncthreads();
        for (int k = 0; k < 16; k++) {
            if (t < 128) red[t] = Wnm[(129 + k) * 128 + t] * m;
            __syncthreads();
            for (int s = 64; s > 0; s >>= 1) { if (t < s) red[t] += red[t + s]; __syncthreads(); }
            if (t == 0) sc[2 + k] = red[0];
            __syncthreads();
        }
    } else {
        int idx = (blockIdx.x - 1) * 256 + t;   // 65*128 outputs (row 64 = bias)
        if (idx >= 65 * 128) return;
        int j = idx >> 7, c = idx & 127;
        const float* row = (j < 64) ? &W2[j * 128] : b2;
        float acc = 0.f;
        for (int cp = 0; cp < 128; cp++) acc = fmaf(row[cp], Wnm[cp * 128 + c], acc);
        if (j < 64) Wc[j * 128 + c] = __float2half_rn(acc);
        else bc[c] = acc;
    }
}

// ---------- t1(fp16) = lrelu(feat@W1 + b1, 0.1); bd fused (lane col==0) ----------
__global__ void __launch_bounds__(256, 4) k_t1(const float* __restrict__ feat,
                                               const float* __restrict__ W1,
                                               const float* __restrict__ b1,
                                               const float* __restrict__ sc,
                                               __half* __restrict__ t1h,
                                               float* __restrict__ bd, int n) {
    int col = threadIdx.x & 63;
    int rg  = threadIdx.x >> 6;
    float w[16];
#pragma unroll
    for (int k = 0; k < 16; k++) w[k] = W1[k * 64 + col];
    float qb[16];
#pragma unroll
    for (int k = 0; k < 16; k++) qb[k] = sc[2 + k];
    float b = b1[col];
    for (int i = blockIdx.x * 4 + rg; i < n; i += gridDim.x * 4) {
        const float4* fr = (const float4*)(feat + (size_t)i * 16);
        float4 f0 = fr[0], f1 = fr[1], f2 = fr[2], f3 = fr[3];
        float acc = b;
        acc = fmaf(f0.x, w[0], acc);  acc = fmaf(f0.y, w[1], acc);
        acc = fmaf(f0.z, w[2], acc);  acc = fmaf(f0.w, w[3], acc);
        acc = fmaf(f1.x, w[4], acc);  acc = fmaf(f1.y, w[5], acc);
        acc = fmaf(f1.z, w[6], acc);  acc = fmaf(f1.w, w[7], acc);
        acc = fmaf(f2.x, w[8], acc);  acc = fmaf(f2.y, w[9], acc);
        acc = fmaf(f2.z, w[10], acc); acc = fmaf(f2.w, w[11], acc);
        acc = fmaf(f3.x, w[12], acc); acc = fmaf(f3.y, w[13], acc);
        acc = fmaf(f3.z, w[14], acc); acc = fmaf(f3.w, w[15], acc);
        t1h[(size_t)i * 64 + col] = __float2half_rn(lrelu(acc, 0.1f));
        if (col == 0) {
            float bacc = 0.f;
            bacc = fmaf(f0.x, qb[0], bacc);  bacc = fmaf(f0.y, qb[1], bacc);
            bacc = fmaf(f0.z, qb[2], bacc);  bacc = fmaf(f0.w, qb[3], bacc);
            bacc = fmaf(f1.x, qb[4], bacc);  bacc = fmaf(f1.y, qb[5], bacc);
            bacc = fmaf(f1.z, qb[6], bacc);  bacc = fmaf(f1.w, qb[7], bacc);
            bacc = fmaf(f2.x, qb[8], bacc);  bacc = fmaf(f2.y, qb[9], bacc);
            bacc = fmaf(f2.z, qb[10], bacc); bacc = fmaf(f2.w, qb[11], bacc);
            bacc = fmaf(f3.x, qb[12], bacc); bacc = fmaf(f3.y, qb[13], bacc);
            bacc = fmaf(f3.z, qb[14], bacc); bacc = fmaf(f3.w, qb[15], bacc);
            bd[i] = bacc;
        }
    }
}

// ---------- A(fp16) = t1h @ Wc + bc ; a_s = A@m   [N,64]@[64,128], MFMA ----------
__global__ void __launch_bounds__(256) k_A(const __half* __restrict__ t1h,
                                           const __half* __restrict__ Wc,
                                           const float* __restrict__ bc,
                                           const float* __restrict__ attn,
                                           __half* __restrict__ Ah,
                                           float* __restrict__ a_s,
                                           int n, int ntiles) {
    __shared__ __half Wt[128 * 72];   // Wt[c][k], stride 72: 16B-aligned
    int t = threadIdx.x;
    for (int idx = t; idx < 64 * 128; idx += 256) {
        int k = idx >> 7, c = idx & 127;
        Wt[c * 72 + k] = Wc[idx];
    }
    __syncthreads();
    int wave = t >> 6, lane = t & 63;
    int c = lane & 15, q = lane >> 4;
    float attv[8], bcv[8];
#pragma unroll
    for (int ct = 0; ct < 8; ct++) {
        attv[ct] = attn[ct * 16 + c];
        bcv[ct]  = bc[ct * 16 + c];
    }
    for (int tile = blockIdx.x * 4 + wave; tile < ntiles; tile += gridDim.x * 4) {
        int rowbase = tile * 16;
        int rm = min(rowbase + c, n - 1);
        h8 af[2];
#pragma unroll
        for (int ks = 0; ks < 2; ks++)
            af[ks] = *(const h8*)&t1h[(size_t)rm * 64 + ks * 32 + q * 8];
        f4 acc[8];
#pragma unroll
        for (int ct = 0; ct < 8; ct++) acc[ct] = (f4)(0.f);
#pragma unroll
        for (int ct = 0; ct < 8; ct++) {
#pragma unroll
            for (int ks = 0; ks < 2; ks++) {
                h8 bf = *(const h8*)&Wt[(ct * 16 + c) * 72 + ks * 32 + q * 8];
                acc[ct] = __builtin_amdgcn_mfma_f32_16x16x32_f16(af[ks], bf, acc[ct], 0, 0, 0);
            }
        }
        int rlim = n - rowbase;
        float s0 = 0.f, s1 = 0.f, s2 = 0.f, s3 = 0.f;
#pragma unroll
        for (int ct = 0; ct < 8; ct++) {
            int col = ct * 16 + c;
            float v0 = acc[ct][0] + bcv[ct];
            float v1 = acc[ct][1] + bcv[ct];
            float v2 = acc[ct][2] + bcv[ct];
            float v3 = acc[ct][3] + bcv[ct];
            if (q * 4 + 0 < rlim) Ah[(size_t)(rowbase + q * 4 + 0) * 128 + col] = __float2half_rn(v0);
            if (q * 4 + 1 < rlim) Ah[(size_t)(rowbase + q * 4 + 1) * 128 + col] = __float2half_rn(v1);
            if (q * 4 + 2 < rlim) Ah[(size_t)(rowbase + q * 4 + 2) * 128 + col] = __float2half_rn(v2);
            if (q * 4 + 3 < rlim) Ah[(size_t)(rowbase + q * 4 + 3) * 128 + col] = __float2half_rn(v3);
            s0 = fmaf(v0, attv[ct], s0);
            s1 = fmaf(v1, attv[ct], s1);
            s2 = fmaf(v2, attv[ct], s2);
            s3 = fmaf(v3, attv[ct], s3);
        }
#pragma unroll
        for (int off = 1; off < 16; off <<= 1) {
            s0 += __shfl_xor(s0, off, 64);
            s1 += __shfl_xor(s1, off, 64);
            s2 += __shfl_xor(s2, off, 64);
            s3 += __shfl_xor(s3, off, 64);
        }
        if (c == 0) {
            if (q * 4 + 0 < rlim) a_s[rowbase + q * 4 + 0] = s0;
            if (q * 4 + 1 < rlim) a_s[rowbase + q * 4 + 1] = s1;
            if (q * 4 + 2 < rlim) a_s[rowbase + q * 4 + 2] = s2;
            if (q * 4 + 3 < rlim) a_s[rowbase + q * 4 + 3] = s3;
        }
    }
}

// ---------- fill CSR: ONE 16B record {src, w, w*bit, pad} per edge (flat) ----------
__global__ void k_fill(const int* __restrict__ src, const int* __restrict__ dst,
                       const float* __restrict__ bit, int* __restrict__ cursor,
                       const float* __restrict__ a_s, const float* __restrict__ bd,
                       const float* __restrict__ sc, float4* __restrict__ recs, int E) {
    int e = blockIdx.x * blockDim.x + threadIdx.x;
    if (e >= E) return;
    int s = src[e], d = dst[e];
    float bv = bit[e];
    float logit = a_s[s] + sc[0] * bv + bd[d] + sc[1];
    float w = __expf(lrelu(logit, 0.2f));
    int p = atomicAdd(&cursor[d], 1);
    recs[p] = make_float4(__int_as_float(s), w, w * bv, 0.f);
}

// ---------- per-node aggregate -> h_node fp16; 64 thr, 2 ch/thread ----------
__global__ void __launch_bounds__(64, 4) k_node(const float* __restrict__ feat,
                                                const float* __restrict__ Wnm,
                                                const float* __restrict__ b_nm,
                                                const __half* __restrict__ Ah,
                                                const int* __restrict__ row_off,
                                                const float4* __restrict__ recs,
                                                __half* __restrict__ h_node) {
    int v = blockIdx.x;
    int t = threadIdx.x;
    int rs = row_off[v], re = row_off[v + 1];
    h2f* outp = (h2f*)&h_node[(size_t)v * 128 + 2 * t];
    const float4* fr = (const float4*)(feat + (size_t)v * 16);
    float fv[16];
    *(float4*)&fv[0]  = fr[0];
    *(float4*)&fv[4]  = fr[1];
    *(float4*)&fv[8]  = fr[2];
    *(float4*)&fv[12] = fr[3];
    float Bx = 0.f, By = 0.f;
#pragma unroll
    for (int k = 0; k < 16; k++) {
        float2 wr = *(const float2*)&Wnm[(129 + k) * 128 + 2 * t];
        Bx = fmaf(fv[k], wr.x, Bx);
        By = fmaf(fv[k], wr.y, By);
    }
    if (re == rs) { h2f z; z[0] = (_Float16)0.f; z[1] = (_Float16)0.f; *outp = z; return; }
    float ax = 0.f, ay = 0.f, sw = 0.f, swb = 0.f;
#pragma unroll 8
    for (int p = rs; p < re; ++p) {
        float4 rec = recs[p];
        int sv = __float_as_int(rec.x);
        float2 av = __half22float2(*(const __half2*)&Ah[(size_t)sv * 128 + 2 * t]);
        ax = fmaf(rec.y, av.x, ax);
        ay = fmaf(rec.y, av.y, ay);
        sw += rec.y;
        swb += rec.z;
    }
    float inv = 1.f / sw;
    float2 wb = *(const float2*)&Wnm[128 * 128 + 2 * t];
    float2 bn = *(const float2*)&b_nm[2 * t];
    float hx = fmaf(swb * inv, wb.x, ax * inv) + Bx + bn.x;
    float hy = fmaf(swb * inv, wb.y, ay * inv) + By + bn.y;
    h2f o; o[0] = (_Float16)fmaxf(hx, 0.f); o[1] = (_Float16)fmaxf(hy, 0.f);
    *outp = o;
}

// ---------- out = bo2 + sum_c lrelu(h_node@Wo1+bo1,0.1)[c]*Wo2[c], MFMA ----------
__global__ void __launch_bounds__(256) k_out(const __half* __restrict__ h_node,
                                             const float* __restrict__ Wo1,
                                             const float* __restrict__ bo1,
                                             const float* __restrict__ Wo2,
                                             const float* __restrict__ bo2,
                                             float* __restrict__ out,
                                             int n, int ntiles) {
    __shared__ __half Wt[128 * 136];
    int t = threadIdx.x;
    for (int idx = t; idx < 128 * 128; idx += 256) {
        int k = idx >> 7, c = idx & 127;
        Wt[c * 136 + k] = __float2half_rn(Wo1[idx]);
    }
    __syncthreads();
    int wave = t >> 6, lane = t & 63;
    int c = lane & 15, q = lane >> 4;
    float b1v[8], w2v[8];
#pragma unroll
    for (int ct = 0; ct < 8; ct++) {
        b1v[ct] = bo1[ct * 16 + c];
        w2v[ct] = Wo2[ct * 16 + c];
    }
    float bias2 = bo2[0];
    for (int tile = blockIdx.x * 4 + wave; tile < ntiles; tile += gridDim.x * 4) {
        int rowbase = tile * 16;
        int rm = min(rowbase + c, n - 1);
        h8 af[4];
#pragma unroll
        for (int ks = 0; ks < 4; ks++)
            af[ks] = *(const h8*)&h_node[(size_t)rm * 128 + ks * 32 + q * 8];
        f4 acc[8];
#pragma unroll
        for (int ct = 0; ct < 8; ct++) acc[ct] = (f4)(0.f);
#pragma unroll
        for (int ct = 0; ct < 8; ct++) {
#pragma unroll
            for (int ks = 0; ks < 4; ks++) {
                h8 bf = *(const h8*)&Wt[(ct * 16 + c) * 136 + ks * 32 + q * 8];
                acc[ct] = __builtin_amdgcn_mfma_f32_16x16x32_f16(af[ks], bf, acc[ct], 0, 0, 0);
            }
        }
        int rlim = n - rowbase;
        float s0 = 0.f, s1 = 0.f, s2 = 0.f, s3 = 0.f;
#pragma unroll
        for (int ct = 0; ct < 8; ct++) {
            s0 = fmaf(lrelu(acc[ct][0] + b1v[ct], 0.1f), w2v[ct], s0);
            s1 = fmaf(lrelu(acc[ct][1] + b1v[ct], 0.1f), w2v[ct], s1);
            s2 = fmaf(lrelu(acc[ct][2] + b1v[ct], 0.1f), w2v[ct], s2);
            s3 = fmaf(lrelu(acc[ct][3] + b1v[ct], 0.1f), w2v[ct], s3);
        }
#pragma unroll
        for (int off = 1; off < 16; off <<= 1) {
            s0 += __shfl_xor(s0, off, 64);
            s1 += __shfl_xor(s1, off, 64);
            s2 += __shfl_xor(s2, off, 64);
            s3 += __shfl_xor(s3, off, 64);
        }
        if (c == 0) {
            if (q * 4 + 0 < rlim) out[rowbase + q * 4 + 0] = bias2 + s0;
            if (q * 4 + 1 < rlim) out[rowbase + q * 4 + 1] = bias2 + s1;
            if (q * 4 + 2 < rlim) out[rowbase + q * 4 + 2] = bias2 + s2;
            if (q * 4 + 3 < rlim) out[rowbase + q * 4 + 3] = bias2 + s3;
        }
    }
}

extern "C" void kernel_launch(void* const* d_in, const int* in_sizes, int n_in,
                              void* d_out, int out_size, void* d_ws, size_t ws_size,
                              hipStream_t stream) {
    const float* feat = (const float*)d_in[0];
    const float* bit  = (const float*)d_in[1];
    const int*   src  = (const int*)d_in[2];
    const int*   dst  = (const int*)d_in[3];
    const float* W1   = (const float*)d_in[4];
    const float* b1   = (const float*)d_in[5];
    const float* W2   = (const float*)d_in[6];
    const float* b2   = (const float*)d_in[7];
    const float* Wnm  = (const float*)d_in[8];
    const float* bnm  = (const float*)d_in[9];
    const float* attn = (const float*)d_in[10];
    const float* Wo1  = (const float*)d_in[11];
    const float* bo1  = (const float*)d_in[12];
    const float* Wo2  = (const float*)d_in[13];
    const float* bo2  = (const float*)d_in[14];
    float* out = (float*)d_out;
    int n = in_sizes[0] / 16;
    int E = in_sizes[2];
    int ntiles = (n + 15) / 16;

    char* wsp = (char*)d_ws;
    size_t off = 0;
    auto alloc = [&](size_t bytes) -> void* {
        void* p = wsp + off;
        off = (off + bytes + 255) & ~(size_t)255;
        return p;
    };
    __half* Ah       = (__half*)alloc((size_t)n * 128 * 2);
    __half* h_node   = (__half*)alloc((size_t)n * 128 * 2);
    __half* t1h      = (__half*)alloc((size_t)n * 64 * 2);
    float*  a_s      = (float*)alloc((size_t)n * 4);
    float*  bd       = (float*)alloc((size_t)n * 4);
    int*    counts   = (int*)alloc((size_t)n * 4);
    int*    row_off  = (int*)alloc((size_t)(n + 1) * 4);
    int*    cursor   = (int*)alloc((size_t)n * 4);
    int*    partials = (int*)alloc(8192);
    float*  sc       = (float*)alloc(256);
    __half* Wc       = (__half*)alloc(64 * 128 * 2);
    float*  bc       = (float*)alloc(128 * 4);
    float4* recs     = (float4*)alloc((size_t)E * 16);

    int nb256 = (n + 255) / 256;
    int eb256 = (E + 255) / 256;
    int nscan = (n + 1023) / 1024;

    hipMemsetAsync(counts, 0, (size_t)n * 4, stream);
    k_hist<<<eb256, 256, 0, stream>>>(dst, counts, E);
    k_scan_a<<<nscan, 256, 0, stream>>>(counts, row_off, partials, n);
    k_scan_b<<<1, 64, 0, stream>>>(partials, nscan);
    k_scan_c<<<nb256, 256, 0, stream>>>(row_off, partials, cursor, n, E);
    k_prep<<<34, 256, 0, stream>>>(W2, b2, Wnm, bnm, attn, Wc, bc, sc);
    k_t1<<<2048, 256, 0, stream>>>(feat, W1, b1, sc, t1h, bd, n);
    k_A<<<1024, 256, 0, stream>>>(t1h, Wc, bc, attn, Ah, a_s, n, ntiles);
    k_fill<<<eb256, 256, 0, stream>>>(src, dst, bit, cursor, a_s, bd, sc, recs, E);
    k_node<<<n, 64, 0, stream>>>(feat, Wnm, bnm, Ah, row_off, recs, h_node);
    k_out<<<1024, 256, 0, stream>>>(h_node, Wo1, bo1, Wo2, bo2, out, n, ntiles);
}

// Round 18
// 392.953 us; speedup vs baseline: 1.3607x; 1.0001x over previous
//
#include <hip/hip_runtime.h>
#include <hip/hip_fp16.h>
#include <math.h>

// Decomposition:
//   t1 = lrelu(feat@W1+b1); A = t1 @ Wc + bc  (Wc=W2@Wnm_top: h only feeds A)
//   a_s = A@m; bd[v] = feat[v]@qb (fused into k_t1)
//   w_e = exp(lrelu(a_s[src] + c1*bit + bd[dst] + c0, 0.2))  (fp32; no max)
//   neigh[v] = (sum w_e*A[src] + (sum w_e*bit)*wbit)/sum_w + B[v] + b_nm
//   out = mlp_out(relu(neigh))
// R1: same-address atomicAdd serializes -> block reduce.
// R6: fp16 A gather. R13: MFMA for dense matvecs.
// R7/R8/R14/R16 (CSR fill): cost = 1 random dirty 64B line/edge (~90us flat
//     floor; granularity-bound — rec size & XCD slicing don't move it).
// R17: mid-tier consolidation (k_bd->k_t1, k_prep, memset).
// R18: k_out was re-staging 64KB fp32 weights per block (64MB redundant fetch,
//     R11 disease). k_prep now pre-converts Wo1->fp16 once; k_out stages fp16
//     via float4 and runs grid 800 (~2 tiles/wave) to amortize.

typedef _Float16 h2f __attribute__((ext_vector_type(2)));
typedef _Float16 h8  __attribute__((ext_vector_type(8)));
typedef float    f4  __attribute__((ext_vector_type(4)));

static __device__ __forceinline__ float lrelu(float x, float s) {
    return x >= 0.f ? x : s * x;
}

__global__ void k_hist(const int* dst, int* counts, int E) {
    int e = blockIdx.x * blockDim.x + threadIdx.x;
    if (e < E) atomicAdd(&counts[dst[e]], 1);
}

__global__ void k_scan_a(const int* counts, int* row_off, int* partials, int n) {
    __shared__ int sd[256];
    int t = threadIdx.x;
    int base = blockIdx.x * 1024 + t * 4;
    int v0 = (base + 0 < n) ? counts[base + 0] : 0;
    int v1 = (base + 1 < n) ? counts[base + 1] : 0;
    int v2 = (base + 2 < n) ? counts[base + 2] : 0;
    int v3 = (base + 3 < n) ? counts[base + 3] : 0;
    int s = v0 + v1 + v2 + v3;
    sd[t] = s; __syncthreads();
    for (int off = 1; off < 256; off <<= 1) {
        int x = (t >= off) ? sd[t - off] : 0;
        __syncthreads();
        sd[t] += x;
        __syncthreads();
    }
    int run = sd[t] - s;
    if (base + 0 < n) row_off[base + 0] = run; run += v0;
    if (base + 1 < n) row_off[base + 1] = run; run += v1;
    if (base + 2 < n) row_off[base + 2] = run; run += v2;
    if (base + 3 < n) row_off[base + 3] = run;
    if (t == 255) partials[blockIdx.x] = sd[255];
}
__global__ void k_scan_b(int* partials, int nb) {
    if (threadIdx.x == 0 && blockIdx.x == 0) {
        int acc = 0;
        for (int i = 0; i < nb; i++) { int x = partials[i]; partials[i] = acc; acc += x; }
    }
}
__global__ void k_scan_c(int* row_off, const int* partials, int* cursor, int n, int E) {
    int i = blockIdx.x * blockDim.x + threadIdx.x;
    if (i < n) {
        int r = row_off[i] + partials[i >> 10];
        row_off[i] = r;
        cursor[i] = r;
    }
    if (i == 0) row_off[n] = E;
}

// ---------- k_prep: blk0 -> sc[]; blk1..33 -> Wc,bc; blk34..97 -> Wo1h ----------
// sc[0]=c1=wbit@m  sc[1]=c0=b_nm@m  sc[2+k]=qb[k]=Wnm[129+k]@m
__global__ void __launch_bounds__(256) k_prep(const float* __restrict__ W2,
                                              const float* __restrict__ b2,
                                              const float* __restrict__ Wnm,
                                              const float* __restrict__ b_nm,
                                              const float* __restrict__ attn,
                                              const float* __restrict__ Wo1,
                                              __half* __restrict__ Wc,
                                              float* __restrict__ bc,
                                              float* __restrict__ sc,
                                              __half* __restrict__ Wo1h) {
    int t = threadIdx.x;
    if (blockIdx.x == 0) {
        __shared__ float red[128];
        float m = (t < 128) ? attn[t] : 0.f;
        if (t < 128) red[t] = Wnm[128 * 128 + t] * m;
        __syncthreads();
        for (int s = 64; s > 0; s >>= 1) { if (t < s) red[t] += red[t + s]; __syncthreads(); }
        if (t == 0) sc[0] = red[0];
        __syncthreads();
        if (t < 128) red[t] = b_nm[t] * m;
        __syncthreads();
        for (int s = 64; s > 0; s >>= 1) { if (t < s) red[t] += red[t + s]; __syncthreads(); }
        if (t == 0) sc[1] = red[0];
        __syncthreads();
        for (int k = 0; k < 16; k++) {
            if (t < 128) red[t] = Wnm[(129 + k) * 128 + t] * m;
            __syncthreads();
            for (int s = 64; s > 0; s >>= 1) { if (t < s) red[t] += red[t + s]; __syncthreads(); }
            if (t == 0) sc[2 + k] = red[0];
            __syncthreads();
        }
    } else if (blockIdx.x <= 33) {
        int idx = (blockIdx.x - 1) * 256 + t;   // 65*128 outputs (row 64 = bias)
        if (idx >= 65 * 128) return;
        int j = idx >> 7, c = idx & 127;
        const float* row = (j < 64) ? &W2[j * 128] : b2;
        float acc = 0.f;
        for (int cp = 0; cp < 128; cp++) acc = fmaf(row[cp], Wnm[cp * 128 + c], acc);
        if (j < 64) Wc[j * 128 + c] = __float2half_rn(acc);
        else bc[c] = acc;
    } else {
        int idx = (blockIdx.x - 34) * 256 + t;  // 16384 Wo1 elements
        if (idx < 128 * 128) Wo1h[idx] = __float2half_rn(Wo1[idx]);
    }
}

// ---------- t1(fp16) = lrelu(feat@W1 + b1, 0.1); bd fused (lane col==0) ----------
__global__ void __launch_bounds__(256, 4) k_t1(const float* __restrict__ feat,
                                               const float* __restrict__ W1,
                                               const float* __restrict__ b1,
                                               const float* __restrict__ sc,
                                               __half* __restrict__ t1h,
                                               float* __restrict__ bd, int n) {
    int col = threadIdx.x & 63;
    int rg  = threadIdx.x >> 6;
    float w[16];
#pragma unroll
    for (int k = 0; k < 16; k++) w[k] = W1[k * 64 + col];
    float qb[16];
#pragma unroll
    for (int k = 0; k < 16; k++) qb[k] = sc[2 + k];
    float b = b1[col];
    for (int i = blockIdx.x * 4 + rg; i < n; i += gridDim.x * 4) {
        const float4* fr = (const float4*)(feat + (size_t)i * 16);
        float4 f0 = fr[0], f1 = fr[1], f2 = fr[2], f3 = fr[3];
        float acc = b;
        acc = fmaf(f0.x, w[0], acc);  acc = fmaf(f0.y, w[1], acc);
        acc = fmaf(f0.z, w[2], acc);  acc = fmaf(f0.w, w[3], acc);
        acc = fmaf(f1.x, w[4], acc);  acc = fmaf(f1.y, w[5], acc);
        acc = fmaf(f1.z, w[6], acc);  acc = fmaf(f1.w, w[7], acc);
        acc = fmaf(f2.x, w[8], acc);  acc = fmaf(f2.y, w[9], acc);
        acc = fmaf(f2.z, w[10], acc); acc = fmaf(f2.w, w[11], acc);
        acc = fmaf(f3.x, w[12], acc); acc = fmaf(f3.y, w[13], acc);
        acc = fmaf(f3.z, w[14], acc); acc = fmaf(f3.w, w[15], acc);
        t1h[(size_t)i * 64 + col] = __float2half_rn(lrelu(acc, 0.1f));
        if (col == 0) {
            float bacc = 0.f;
            bacc = fmaf(f0.x, qb[0], bacc);  bacc = fmaf(f0.y, qb[1], bacc);
            bacc = fmaf(f0.z, qb[2], bacc);  bacc = fmaf(f0.w, qb[3], bacc);
            bacc = fmaf(f1.x, qb[4], bacc);  bacc = fmaf(f1.y, qb[5], bacc);
            bacc = fmaf(f1.z, qb[6], bacc);  bacc = fmaf(f1.w, qb[7], bacc);
            bacc = fmaf(f2.x, qb[8], bacc);  bacc = fmaf(f2.y, qb[9], bacc);
            bacc = fmaf(f2.z, qb[10], bacc); bacc = fmaf(f2.w, qb[11], bacc);
            bacc = fmaf(f3.x, qb[12], bacc); bacc = fmaf(f3.y, qb[13], bacc);
            bacc = fmaf(f3.z, qb[14], bacc); bacc = fmaf(f3.w, qb[15], bacc);
            bd[i] = bacc;
        }
    }
}

// ---------- A(fp16) = t1h @ Wc + bc ; a_s = A@m   [N,64]@[64,128], MFMA ----------
__global__ void __launch_bounds__(256) k_A(const __half* __restrict__ t1h,
                                           const __half* __restrict__ Wc,
                                           const float* __restrict__ bc,
                                           const float* __restrict__ attn,
                                           __half* __restrict__ Ah,
                                           float* __restrict__ a_s,
                                           int n, int ntiles) {
    __shared__ __half Wt[128 * 72];   // Wt[c][k], stride 72: 16B-aligned
    int t = threadIdx.x;
    for (int idx = t; idx < 64 * 128; idx += 256) {
        int k = idx >> 7, c = idx & 127;
        Wt[c * 72 + k] = Wc[idx];
    }
    __syncthreads();
    int wave = t >> 6, lane = t & 63;
    int c = lane & 15, q = lane >> 4;
    float attv[8], bcv[8];
#pragma unroll
    for (int ct = 0; ct < 8; ct++) {
        attv[ct] = attn[ct * 16 + c];
        bcv[ct]  = bc[ct * 16 + c];
    }
    for (int tile = blockIdx.x * 4 + wave; tile < ntiles; tile += gridDim.x * 4) {
        int rowbase = tile * 16;
        int rm = min(rowbase + c, n - 1);
        h8 af[2];
#pragma unroll
        for (int ks = 0; ks < 2; ks++)
            af[ks] = *(const h8*)&t1h[(size_t)rm * 64 + ks * 32 + q * 8];
        f4 acc[8];
#pragma unroll
        for (int ct = 0; ct < 8; ct++) acc[ct] = (f4)(0.f);
#pragma unroll
        for (int ct = 0; ct < 8; ct++) {
#pragma unroll
            for (int ks = 0; ks < 2; ks++) {
                h8 bf = *(const h8*)&Wt[(ct * 16 + c) * 72 + ks * 32 + q * 8];
                acc[ct] = __builtin_amdgcn_mfma_f32_16x16x32_f16(af[ks], bf, acc[ct], 0, 0, 0);
            }
        }
        int rlim = n - rowbase;
        float s0 = 0.f, s1 = 0.f, s2 = 0.f, s3 = 0.f;
#pragma unroll
        for (int ct = 0; ct < 8; ct++) {
            int col = ct * 16 + c;
            float v0 = acc[ct][0] + bcv[ct];
            float v1 = acc[ct][1] + bcv[ct];
            float v2 = acc[ct][2] + bcv[ct];
            float v3 = acc[ct][3] + bcv[ct];
            if (q * 4 + 0 < rlim) Ah[(size_t)(rowbase + q * 4 + 0) * 128 + col] = __float2half_rn(v0);
            if (q * 4 + 1 < rlim) Ah[(size_t)(rowbase + q * 4 + 1) * 128 + col] = __float2half_rn(v1);
            if (q * 4 + 2 < rlim) Ah[(size_t)(rowbase + q * 4 + 2) * 128 + col] = __float2half_rn(v2);
            if (q * 4 + 3 < rlim) Ah[(size_t)(rowbase + q * 4 + 3) * 128 + col] = __float2half_rn(v3);
            s0 = fmaf(v0, attv[ct], s0);
            s1 = fmaf(v1, attv[ct], s1);
            s2 = fmaf(v2, attv[ct], s2);
            s3 = fmaf(v3, attv[ct], s3);
        }
#pragma unroll
        for (int off = 1; off < 16; off <<= 1) {
            s0 += __shfl_xor(s0, off, 64);
            s1 += __shfl_xor(s1, off, 64);
            s2 += __shfl_xor(s2, off, 64);
            s3 += __shfl_xor(s3, off, 64);
        }
        if (c == 0) {
            if (q * 4 + 0 < rlim) a_s[rowbase + q * 4 + 0] = s0;
            if (q * 4 + 1 < rlim) a_s[rowbase + q * 4 + 1] = s1;
            if (q * 4 + 2 < rlim) a_s[rowbase + q * 4 + 2] = s2;
            if (q * 4 + 3 < rlim) a_s[rowbase + q * 4 + 3] = s3;
        }
    }
}

// ---------- fill CSR: ONE 16B record {src, w, w*bit, pad} per edge (flat) ----------
__global__ void k_fill(const int* __restrict__ src, const int* __restrict__ dst,
                       const float* __restrict__ bit, int* __restrict__ cursor,
                       const float* __restrict__ a_s, const float* __restrict__ bd,
                       const float* __restrict__ sc, float4* __restrict__ recs, int E) {
    int e = blockIdx.x * blockDim.x + threadIdx.x;
    if (e >= E) return;
    int s = src[e], d = dst[e];
    float bv = bit[e];
    float logit = a_s[s] + sc[0] * bv + bd[d] + sc[1];
    float w = __expf(lrelu(logit, 0.2f));
    int p = atomicAdd(&cursor[d], 1);
    recs[p] = make_float4(__int_as_float(s), w, w * bv, 0.f);
}

// ---------- per-node aggregate -> h_node fp16; 64 thr, 2 ch/thread ----------
__global__ void __launch_bounds__(64, 4) k_node(const float* __restrict__ feat,
                                                const float* __restrict__ Wnm,
                                                const float* __restrict__ b_nm,
                                                const __half* __restrict__ Ah,
                                                const int* __restrict__ row_off,
                                                const float4* __restrict__ recs,
                                                __half* __restrict__ h_node) {
    int v = blockIdx.x;
    int t = threadIdx.x;
    int rs = row_off[v], re = row_off[v + 1];
    h2f* outp = (h2f*)&h_node[(size_t)v * 128 + 2 * t];
    const float4* fr = (const float4*)(feat + (size_t)v * 16);
    float fv[16];
    *(float4*)&fv[0]  = fr[0];
    *(float4*)&fv[4]  = fr[1];
    *(float4*)&fv[8]  = fr[2];
    *(float4*)&fv[12] = fr[3];
    float Bx = 0.f, By = 0.f;
#pragma unroll
    for (int k = 0; k < 16; k++) {
        float2 wr = *(const float2*)&Wnm[(129 + k) * 128 + 2 * t];
        Bx = fmaf(fv[k], wr.x, Bx);
        By = fmaf(fv[k], wr.y, By);
    }
    if (re == rs) { h2f z; z[0] = (_Float16)0.f; z[1] = (_Float16)0.f; *outp = z; return; }
    float ax = 0.f, ay = 0.f, sw = 0.f, swb = 0.f;
#pragma unroll 8
    for (int p = rs; p < re; ++p) {
        float4 rec = recs[p];
        int sv = __float_as_int(rec.x);
        float2 av = __half22float2(*(const __half2*)&Ah[(size_t)sv * 128 + 2 * t]);
        ax = fmaf(rec.y, av.x, ax);
        ay = fmaf(rec.y, av.y, ay);
        sw += rec.y;
        swb += rec.z;
    }
    float inv = 1.f / sw;
    float2 wb = *(const float2*)&Wnm[128 * 128 + 2 * t];
    float2 bn = *(const float2*)&b_nm[2 * t];
    float hx = fmaf(swb * inv, wb.x, ax * inv) + Bx + bn.x;
    float hy = fmaf(swb * inv, wb.y, ay * inv) + By + bn.y;
    h2f o; o[0] = (_Float16)fmaxf(hx, 0.f); o[1] = (_Float16)fmaxf(hy, 0.f);
    *outp = o;
}

// ---------- out = bo2 + sum_c lrelu(h_node@Wo1+bo1,0.1)[c]*Wo2[c], MFMA ----------
__global__ void __launch_bounds__(256) k_out(const __half* __restrict__ h_node,
                                             const __half* __restrict__ Wo1h,
                                             const float* __restrict__ bo1,
                                             const float* __restrict__ Wo2,
                                             const float* __restrict__ bo2,
                                             float* __restrict__ out,
                                             int n, int ntiles) {
    __shared__ __half Wt[128 * 136];
    int t = threadIdx.x;
    // stage fp16 weights transposed: Wt[c][k] = Wo1h[k*128+c]
    for (int idx = t; idx < 128 * 128; idx += 256) {
        int k = idx >> 7, c = idx & 127;
        Wt[c * 136 + k] = Wo1h[idx];
    }
    __syncthreads();
    int wave = t >> 6, lane = t & 63;
    int c = lane & 15, q = lane >> 4;
    float b1v[8], w2v[8];
#pragma unroll
    for (int ct = 0; ct < 8; ct++) {
        b1v[ct] = bo1[ct * 16 + c];
        w2v[ct] = Wo2[ct * 16 + c];
    }
    float bias2 = bo2[0];
    for (int tile = blockIdx.x * 4 + wave; tile < ntiles; tile += gridDim.x * 4) {
        int rowbase = tile * 16;
        int rm = min(rowbase + c, n - 1);
        h8 af[4];
#pragma unroll
        for (int ks = 0; ks < 4; ks++)
            af[ks] = *(const h8*)&h_node[(size_t)rm * 128 + ks * 32 + q * 8];
        f4 acc[8];
#pragma unroll
        for (int ct = 0; ct < 8; ct++) acc[ct] = (f4)(0.f);
#pragma unroll
        for (int ct = 0; ct < 8; ct++) {
#pragma unroll
            for (int ks = 0; ks < 4; ks++) {
                h8 bf = *(const h8*)&Wt[(ct * 16 + c) * 136 + ks * 32 + q * 8];
                acc[ct] = __builtin_amdgcn_mfma_f32_16x16x32_f16(af[ks], bf, acc[ct], 0, 0, 0);
            }
        }
        int rlim = n - rowbase;
        float s0 = 0.f, s1 = 0.f, s2 = 0.f, s3 = 0.f;
#pragma unroll
        for (int ct = 0; ct < 8; ct++) {
            s0 = fmaf(lrelu(acc[ct][0] + b1v[ct], 0.1f), w2v[ct], s0);
            s1 = fmaf(lrelu(acc[ct][1] + b1v[ct], 0.1f), w2v[ct], s1);
            s2 = fmaf(lrelu(acc[ct][2] + b1v[ct], 0.1f), w2v[ct], s2);
            s3 = fmaf(lrelu(acc[ct][3] + b1v[ct], 0.1f), w2v[ct], s3);
        }
#pragma unroll
        for (int off = 1; off < 16; off <<= 1) {
            s0 += __shfl_xor(s0, off, 64);
            s1 += __shfl_xor(s1, off, 64);
            s2 += __shfl_xor(s2, off, 64);
            s3 += __shfl_xor(s3, off, 64);
        }
        if (c == 0) {
            if (q * 4 + 0 < rlim) out[rowbase + q * 4 + 0] = bias2 + s0;
            if (q * 4 + 1 < rlim) out[rowbase + q * 4 + 1] = bias2 + s1;
            if (q * 4 + 2 < rlim) out[rowbase + q * 4 + 2] = bias2 + s2;
            if (q * 4 + 3 < rlim) out[rowbase + q * 4 + 3] = bias2 + s3;
        }
    }
}

extern "C" void kernel_launch(void* const* d_in, const int* in_sizes, int n_in,
                              void* d_out, int out_size, void* d_ws, size_t ws_size,
                              hipStream_t stream) {
    const float* feat = (const float*)d_in[0];
    const float* bit  = (const float*)d_in[1];
    const int*   src  = (const int*)d_in[2];
    const int*   dst  = (const int*)d_in[3];
    const float* W1   = (const float*)d_in[4];
    const float* b1   = (const float*)d_in[5];
    const float* W2   = (const float*)d_in[6];
    const float* b2   = (const float*)d_in[7];
    const float* Wnm  = (const float*)d_in[8];
    const float* bnm  = (const float*)d_in[9];
    const float* attn = (const float*)d_in[10];
    const float* Wo1  = (const float*)d_in[11];
    const float* bo1  = (const float*)d_in[12];
    const float* Wo2  = (const float*)d_in[13];
    const float* bo2  = (const float*)d_in[14];
    float* out = (float*)d_out;
    int n = in_sizes[0] / 16;
    int E = in_sizes[2];
    int ntiles = (n + 15) / 16;

    char* wsp = (char*)d_ws;
    size_t off = 0;
    auto alloc = [&](size_t bytes) -> void* {
        void* p = wsp + off;
        off = (off + bytes + 255) & ~(size_t)255;
        return p;
    };
    __half* Ah       = (__half*)alloc((size_t)n * 128 * 2);
    __half* h_node   = (__half*)alloc((size_t)n * 128 * 2);
    __half* t1h      = (__half*)alloc((size_t)n * 64 * 2);
    float*  a_s      = (float*)alloc((size_t)n * 4);
    float*  bd       = (float*)alloc((size_t)n * 4);
    int*    counts   = (int*)alloc((size_t)n * 4);
    int*    row_off  = (int*)alloc((size_t)(n + 1) * 4);
    int*    cursor   = (int*)alloc((size_t)n * 4);
    int*    partials = (int*)alloc(8192);
    float*  sc       = (float*)alloc(256);
    __half* Wc       = (__half*)alloc(64 * 128 * 2);
    float*  bc       = (float*)alloc(128 * 4);
    __half* Wo1h     = (__half*)alloc(128 * 128 * 2);
    float4* recs     = (float4*)alloc((size_t)E * 16);

    int nb256 = (n + 255) / 256;
    int eb256 = (E + 255) / 256;
    int nscan = (n + 1023) / 1024;

    hipMemsetAsync(counts, 0, (size_t)n * 4, stream);
    k_hist<<<eb256, 256, 0, stream>>>(dst, counts, E);
    k_scan_a<<<nscan, 256, 0, stream>>>(counts, row_off, partials, n);
    k_scan_b<<<1, 64, 0, stream>>>(partials, nscan);
    k_scan_c<<<nb256, 256, 0, stream>>>(row_off, partials, cursor, n, E);
    k_prep<<<98, 256, 0, stream>>>(W2, b2, Wnm, bnm, attn, Wo1, Wc, bc, sc, Wo1h);
    k_t1<<<2048, 256, 0, stream>>>(feat, W1, b1, sc, t1h, bd, n);
    k_A<<<1024, 256, 0, stream>>>(t1h, Wc, bc, attn, Ah, a_s, n, ntiles);
    k_fill<<<eb256, 256, 0, stream>>>(src, dst, bit, cursor, a_s, bd, sc, recs, E);
    k_node<<<n, 64, 0, stream>>>(feat, Wnm, bnm, Ah, row_off, recs, h_node);
    k_out<<<800, 256, 0, stream>>>(h_node, Wo1h, bo1, Wo2, bo2, out, n, ntiles);
}

// Round 19
// 378.800 us; speedup vs baseline: 1.4115x; 1.0374x over previous
//
#include <hip/hip_runtime.h>
#include <hip/hip_fp16.h>
#include <math.h>

// Decomposition:
//   t1 = lrelu(feat@W1+b1) (computed in-wave inside k_A, R19)
//   A = t1 @ Wc + bc  (Wc=W2@Wnm_top: h only feeds A)
//   a_s = A@m; bd[v] = feat[v]@qb (also fused into k_A)
//   w_e = exp(lrelu(a_s[src] + c1*bit + bd[dst] + c0, 0.2))  (fp32; no max)
//   neigh[v] = (sum w_e*A[src] + (sum w_e*bit)*wbit)/sum_w + B[v] + b_nm
//   out = mlp_out(relu(neigh))
// R1: same-address atomicAdd serializes -> block reduce.
// R6: fp16 A gather. R13: MFMA for dense matvecs.
// R7/R8/R14/R16 (CSR fill): 1 random dirty 64B line/edge = ~90us flat floor.
// R17/R18: mid-tier is dispatch+latency bound, not traffic bound (R18's 64MB
//     weight-fetch cut was a no-op: it was L2-served).
// R19: cut dispatches 11->9: t1+bd fused into k_A (per-wave scalar t1 into
//     LDS slice, in-wave handoff to MFMA A-frags; kills 25MB t1h round-trip);
//     scan_b folded into scan_c (per-thread serial prefix of <=98 partials).

typedef _Float16 h2f __attribute__((ext_vector_type(2)));
typedef _Float16 h8  __attribute__((ext_vector_type(8)));
typedef float    f4  __attribute__((ext_vector_type(4)));

static __device__ __forceinline__ float lrelu(float x, float s) {
    return x >= 0.f ? x : s * x;
}

__global__ void k_hist(const int* dst, int* counts, int E) {
    int e = blockIdx.x * blockDim.x + threadIdx.x;
    if (e < E) atomicAdd(&counts[dst[e]], 1);
}

__global__ void k_scan_a(const int* counts, int* row_off, int* partials, int n) {
    __shared__ int sd[256];
    int t = threadIdx.x;
    int base = blockIdx.x * 1024 + t * 4;
    int v0 = (base + 0 < n) ? counts[base + 0] : 0;
    int v1 = (base + 1 < n) ? counts[base + 1] : 0;
    int v2 = (base + 2 < n) ? counts[base + 2] : 0;
    int v3 = (base + 3 < n) ? counts[base + 3] : 0;
    int s = v0 + v1 + v2 + v3;
    sd[t] = s; __syncthreads();
    for (int off = 1; off < 256; off <<= 1) {
        int x = (t >= off) ? sd[t - off] : 0;
        __syncthreads();
        sd[t] += x;
        __syncthreads();
    }
    int run = sd[t] - s;
    if (base + 0 < n) row_off[base + 0] = run; run += v0;
    if (base + 1 < n) row_off[base + 1] = run; run += v1;
    if (base + 2 < n) row_off[base + 2] = run; run += v2;
    if (base + 3 < n) row_off[base + 3] = run;
    if (t == 255) partials[blockIdx.x] = sd[255];
}

// scan_c with scan_b folded in: per-thread serial prefix over partials (<=98)
__global__ void k_scan_c(int* row_off, const int* partials, int* cursor, int n, int E) {
    int i = blockIdx.x * blockDim.x + threadIdx.x;
    if (i < n) {
        int g = i >> 10;
        int acc = 0;
        for (int j = 0; j < g; j++) acc += partials[j];
        int r = row_off[i] + acc;
        row_off[i] = r;
        cursor[i] = r;
    }
    if (i == 0) row_off[n] = E;
}

// ---------- k_prep: blk0 -> sc[]; blk1..33 -> Wc,bc ----------
// sc[0]=c1=wbit@m  sc[1]=c0=b_nm@m  sc[2+k]=qb[k]=Wnm[129+k]@m
__global__ void __launch_bounds__(256) k_prep(const float* __restrict__ W2,
                                              const float* __restrict__ b2,
                                              const float* __restrict__ Wnm,
                                              const float* __restrict__ b_nm,
                                              const float* __restrict__ attn,
                                              __half* __restrict__ Wc,
                                              float* __restrict__ bc,
                                              float* __restrict__ sc) {
    int t = threadIdx.x;
    if (blockIdx.x == 0) {
        __shared__ float red[128];
        float m = (t < 128) ? attn[t] : 0.f;
        if (t < 128) red[t] = Wnm[128 * 128 + t] * m;
        __syncthreads();
        for (int s = 64; s > 0; s >>= 1) { if (t < s) red[t] += red[t + s]; __syncthreads(); }
        if (t == 0) sc[0] = red[0];
        __syncthreads();
        if (t < 128) red[t] = b_nm[t] * m;
        __syncthreads();
        for (int s = 64; s > 0; s >>= 1) { if (t < s) red[t] += red[t + s]; __syncthreads(); }
        if (t == 0) sc[1] = red[0];
        __syncthreads();
        for (int k = 0; k < 16; k++) {
            if (t < 128) red[t] = Wnm[(129 + k) * 128 + t] * m;
            __syncthreads();
            for (int s = 64; s > 0; s >>= 1) { if (t < s) red[t] += red[t + s]; __syncthreads(); }
            if (t == 0) sc[2 + k] = red[0];
            __syncthreads();
        }
    } else {
        int idx = (blockIdx.x - 1) * 256 + t;   // 65*128 outputs (row 64 = bias)
        if (idx >= 65 * 128) return;
        int j = idx >> 7, c = idx & 127;
        const float* row = (j < 64) ? &W2[j * 128] : b2;
        float acc = 0.f;
        for (int cp = 0; cp < 128; cp++) acc = fmaf(row[cp], Wnm[cp * 128 + c], acc);
        if (j < 64) Wc[j * 128 + c] = __float2half_rn(acc);
        else bc[c] = acc;
    }
}

// ---------- fused: t1 (in-wave scalar) -> A(fp16) = t1@Wc+bc via MFMA ;
//            a_s = A@m ; bd = feat@qb ----------
__global__ void __launch_bounds__(256) k_A(const float* __restrict__ feat,
                                           const float* __restrict__ W1,
                                           const float* __restrict__ b1,
                                           const float* __restrict__ sc,
                                           const __half* __restrict__ Wc,
                                           const float* __restrict__ bc,
                                           const float* __restrict__ attn,
                                           __half* __restrict__ Ah,
                                           float* __restrict__ a_s,
                                           float* __restrict__ bd,
                                           int n, int ntiles) {
    __shared__ __half Wt[128 * 72];       // Wc^T: Wt[c][k], stride 72
    __shared__ float  W1s[16 * 64];       // W1 staged fp32
    __shared__ float  b1s[64];
    __shared__ __half t1s[4][16 * 72];    // per-wave t1 tile [row][col], stride 72
    int t = threadIdx.x;
    for (int idx = t; idx < 64 * 128; idx += 256) {
        int k = idx >> 7, c = idx & 127;
        Wt[c * 72 + k] = Wc[idx];
    }
    for (int idx = t; idx < 1024; idx += 256) W1s[idx] = W1[idx];
    if (t < 64) b1s[t] = b1[t];
    __syncthreads();
    int wave = t >> 6, lane = t & 63;
    int c = lane & 15, q = lane >> 4;
    float attv[8], bcv[8];
#pragma unroll
    for (int ct = 0; ct < 8; ct++) {
        attv[ct] = attn[ct * 16 + c];
        bcv[ct]  = bc[ct * 16 + c];
    }
    float qb[16];
#pragma unroll
    for (int k = 0; k < 16; k++) qb[k] = sc[2 + k];
    __half* myT1 = &t1s[wave][0];
    for (int tile = blockIdx.x * 4 + wave; tile < ntiles; tile += gridDim.x * 4) {
        int rowbase = tile * 16;
        int rm = min(rowbase + c, n - 1);
        // load feat row rm (all 4 q-groups load same row -> L1 broadcast)
        const float4* fr = (const float4*)(feat + (size_t)rm * 16);
        float fv[16];
        *(float4*)&fv[0]  = fr[0];
        *(float4*)&fv[4]  = fr[1];
        *(float4*)&fv[8]  = fr[2];
        *(float4*)&fv[12] = fr[3];
        // bd (one lane per row)
        if (q == 0 && rowbase + c < n) {
            float bacc = 0.f;
#pragma unroll
            for (int k = 0; k < 16; k++) bacc = fmaf(fv[k], qb[k], bacc);
            bd[rowbase + c] = bacc;
        }
        // t1 row c, cols q*16..q*16+15 (scalar, fp32 then fp16)
        {
            _Float16 tv[16];
#pragma unroll
            for (int jj = 0; jj < 16; jj++) {
                int j = q * 16 + jj;
                float acc = b1s[j];
#pragma unroll
                for (int k = 0; k < 16; k++) acc = fmaf(fv[k], W1s[k * 64 + j], acc);
                tv[jj] = (_Float16)lrelu(acc, 0.1f);
            }
            *(h8*)&myT1[c * 72 + q * 16 + 0] = *(h8*)&tv[0];
            *(h8*)&myT1[c * 72 + q * 16 + 8] = *(h8*)&tv[8];
        }
        // in-wave handoff: read A-frags (compiler inserts lgkmcnt wait)
        h8 af[2];
#pragma unroll
        for (int ks = 0; ks < 2; ks++)
            af[ks] = *(const h8*)&myT1[c * 72 + ks * 32 + q * 8];
        f4 acc[8];
#pragma unroll
        for (int ct = 0; ct < 8; ct++) acc[ct] = (f4)(0.f);
#pragma unroll
        for (int ct = 0; ct < 8; ct++) {
#pragma unroll
            for (int ks = 0; ks < 2; ks++) {
                h8 bf = *(const h8*)&Wt[(ct * 16 + c) * 72 + ks * 32 + q * 8];
                acc[ct] = __builtin_amdgcn_mfma_f32_16x16x32_f16(af[ks], bf, acc[ct], 0, 0, 0);
            }
        }
        int rlim = n - rowbase;
        float s0 = 0.f, s1 = 0.f, s2 = 0.f, s3 = 0.f;
#pragma unroll
        for (int ct = 0; ct < 8; ct++) {
            int col = ct * 16 + c;
            float v0 = acc[ct][0] + bcv[ct];
            float v1 = acc[ct][1] + bcv[ct];
            float v2 = acc[ct][2] + bcv[ct];
            float v3 = acc[ct][3] + bcv[ct];
            if (q * 4 + 0 < rlim) Ah[(size_t)(rowbase + q * 4 + 0) * 128 + col] = __float2half_rn(v0);
            if (q * 4 + 1 < rlim) Ah[(size_t)(rowbase + q * 4 + 1) * 128 + col] = __float2half_rn(v1);
            if (q * 4 + 2 < rlim) Ah[(size_t)(rowbase + q * 4 + 2) * 128 + col] = __float2half_rn(v2);
            if (q * 4 + 3 < rlim) Ah[(size_t)(rowbase + q * 4 + 3) * 128 + col] = __float2half_rn(v3);
            s0 = fmaf(v0, attv[ct], s0);
            s1 = fmaf(v1, attv[ct], s1);
            s2 = fmaf(v2, attv[ct], s2);
            s3 = fmaf(v3, attv[ct], s3);
        }
#pragma unroll
        for (int off = 1; off < 16; off <<= 1) {
            s0 += __shfl_xor(s0, off, 64);
            s1 += __shfl_xor(s1, off, 64);
            s2 += __shfl_xor(s2, off, 64);
            s3 += __shfl_xor(s3, off, 64);
        }
        if (c == 0) {
            if (q * 4 + 0 < rlim) a_s[rowbase + q * 4 + 0] = s0;
            if (q * 4 + 1 < rlim) a_s[rowbase + q * 4 + 1] = s1;
            if (q * 4 + 2 < rlim) a_s[rowbase + q * 4 + 2] = s2;
            if (q * 4 + 3 < rlim) a_s[rowbase + q * 4 + 3] = s3;
        }
    }
}

// ---------- fill CSR: ONE 16B record {src, w, w*bit, pad} per edge (flat) ----------
__global__ void k_fill(const int* __restrict__ src, const int* __restrict__ dst,
                       const float* __restrict__ bit, int* __restrict__ cursor,
                       const float* __restrict__ a_s, const float* __restrict__ bd,
                       const float* __restrict__ sc, float4* __restrict__ recs, int E) {
    int e = blockIdx.x * blockDim.x + threadIdx.x;
    if (e >= E) return;
    int s = src[e], d = dst[e];
    float bv = bit[e];
    float logit = a_s[s] + sc[0] * bv + bd[d] + sc[1];
    float w = __expf(lrelu(logit, 0.2f));
    int p = atomicAdd(&cursor[d], 1);
    recs[p] = make_float4(__int_as_float(s), w, w * bv, 0.f);
}

// ---------- per-node aggregate -> h_node fp16; 64 thr, 2 ch/thread ----------
__global__ void __launch_bounds__(64, 4) k_node(const float* __restrict__ feat,
                                                const float* __restrict__ Wnm,
                                                const float* __restrict__ b_nm,
                                                const __half* __restrict__ Ah,
                                                const int* __restrict__ row_off,
                                                const float4* __restrict__ recs,
                                                __half* __restrict__ h_node) {
    int v = blockIdx.x;
    int t = threadIdx.x;
    int rs = row_off[v], re = row_off[v + 1];
    h2f* outp = (h2f*)&h_node[(size_t)v * 128 + 2 * t];
    const float4* fr = (const float4*)(feat + (size_t)v * 16);
    float fv[16];
    *(float4*)&fv[0]  = fr[0];
    *(float4*)&fv[4]  = fr[1];
    *(float4*)&fv[8]  = fr[2];
    *(float4*)&fv[12] = fr[3];
    float Bx = 0.f, By = 0.f;
#pragma unroll
    for (int k = 0; k < 16; k++) {
        float2 wr = *(const float2*)&Wnm[(129 + k) * 128 + 2 * t];
        Bx = fmaf(fv[k], wr.x, Bx);
        By = fmaf(fv[k], wr.y, By);
    }
    if (re == rs) { h2f z; z[0] = (_Float16)0.f; z[1] = (_Float16)0.f; *outp = z; return; }
    float ax = 0.f, ay = 0.f, sw = 0.f, swb = 0.f;
#pragma unroll 8
    for (int p = rs; p < re; ++p) {
        float4 rec = recs[p];
        int sv = __float_as_int(rec.x);
        float2 av = __half22float2(*(const __half2*)&Ah[(size_t)sv * 128 + 2 * t]);
        ax = fmaf(rec.y, av.x, ax);
        ay = fmaf(rec.y, av.y, ay);
        sw += rec.y;
        swb += rec.z;
    }
    float inv = 1.f / sw;
    float2 wb = *(const float2*)&Wnm[128 * 128 + 2 * t];
    float2 bn = *(const float2*)&b_nm[2 * t];
    float hx = fmaf(swb * inv, wb.x, ax * inv) + Bx + bn.x;
    float hy = fmaf(swb * inv, wb.y, ay * inv) + By + bn.y;
    h2f o; o[0] = (_Float16)fmaxf(hx, 0.f); o[1] = (_Float16)fmaxf(hy, 0.f);
    *outp = o;
}

// ---------- out = bo2 + sum_c lrelu(h_node@Wo1+bo1,0.1)[c]*Wo2[c], MFMA ----------
__global__ void __launch_bounds__(256) k_out(const __half* __restrict__ h_node,
                                             const float* __restrict__ Wo1,
                                             const float* __restrict__ bo1,
                                             const float* __restrict__ Wo2,
                                             const float* __restrict__ bo2,
                                             float* __restrict__ out,
                                             int n, int ntiles) {
    __shared__ __half Wt[128 * 136];
    int t = threadIdx.x;
    for (int idx = t; idx < 128 * 128; idx += 256) {
        int k = idx >> 7, c = idx & 127;
        Wt[c * 136 + k] = __float2half_rn(Wo1[idx]);
    }
    __syncthreads();
    int wave = t >> 6, lane = t & 63;
    int c = lane & 15, q = lane >> 4;
    float b1v[8], w2v[8];
#pragma unroll
    for (int ct = 0; ct < 8; ct++) {
        b1v[ct] = bo1[ct * 16 + c];
        w2v[ct] = Wo2[ct * 16 + c];
    }
    float bias2 = bo2[0];
    for (int tile = blockIdx.x * 4 + wave; tile < ntiles; tile += gridDim.x * 4) {
        int rowbase = tile * 16;
        int rm = min(rowbase + c, n - 1);
        h8 af[4];
#pragma unroll
        for (int ks = 0; ks < 4; ks++)
            af[ks] = *(const h8*)&h_node[(size_t)rm * 128 + ks * 32 + q * 8];
        f4 acc[8];
#pragma unroll
        for (int ct = 0; ct < 8; ct++) acc[ct] = (f4)(0.f);
#pragma unroll
        for (int ct = 0; ct < 8; ct++) {
#pragma unroll
            for (int ks = 0; ks < 4; ks++) {
                h8 bf = *(const h8*)&Wt[(ct * 16 + c) * 136 + ks * 32 + q * 8];
                acc[ct] = __builtin_amdgcn_mfma_f32_16x16x32_f16(af[ks], bf, acc[ct], 0, 0, 0);
            }
        }
        int rlim = n - rowbase;
        float s0 = 0.f, s1 = 0.f, s2 = 0.f, s3 = 0.f;
#pragma unroll
        for (int ct = 0; ct < 8; ct++) {
            s0 = fmaf(lrelu(acc[ct][0] + b1v[ct], 0.1f), w2v[ct], s0);
            s1 = fmaf(lrelu(acc[ct][1] + b1v[ct], 0.1f), w2v[ct], s1);
            s2 = fmaf(lrelu(acc[ct][2] + b1v[ct], 0.1f), w2v[ct], s2);
            s3 = fmaf(lrelu(acc[ct][3] + b1v[ct], 0.1f), w2v[ct], s3);
        }
#pragma unroll
        for (int off = 1; off < 16; off <<= 1) {
            s0 += __shfl_xor(s0, off, 64);
            s1 += __shfl_xor(s1, off, 64);
            s2 += __shfl_xor(s2, off, 64);
            s3 += __shfl_xor(s3, off, 64);
        }
        if (c == 0) {
            if (q * 4 + 0 < rlim) out[rowbase + q * 4 + 0] = bias2 + s0;
            if (q * 4 + 1 < rlim) out[rowbase + q * 4 + 1] = bias2 + s1;
            if (q * 4 + 2 < rlim) out[rowbase + q * 4 + 2] = bias2 + s2;
            if (q * 4 + 3 < rlim) out[rowbase + q * 4 + 3] = bias2 + s3;
        }
    }
}

extern "C" void kernel_launch(void* const* d_in, const int* in_sizes, int n_in,
                              void* d_out, int out_size, void* d_ws, size_t ws_size,
                              hipStream_t stream) {
    const float* feat = (const float*)d_in[0];
    const float* bit  = (const float*)d_in[1];
    const int*   src  = (const int*)d_in[2];
    const int*   dst  = (const int*)d_in[3];
    const float* W1   = (const float*)d_in[4];
    const float* b1   = (const float*)d_in[5];
    const float* W2   = (const float*)d_in[6];
    const float* b2   = (const float*)d_in[7];
    const float* Wnm  = (const float*)d_in[8];
    const float* bnm  = (const float*)d_in[9];
    const float* attn = (const float*)d_in[10];
    const float* Wo1  = (const float*)d_in[11];
    const float* bo1  = (const float*)d_in[12];
    const float* Wo2  = (const float*)d_in[13];
    const float* bo2  = (const float*)d_in[14];
    float* out = (float*)d_out;
    int n = in_sizes[0] / 16;
    int E = in_sizes[2];
    int ntiles = (n + 15) / 16;

    char* wsp = (char*)d_ws;
    size_t off = 0;
    auto alloc = [&](size_t bytes) -> void* {
        void* p = wsp + off;
        off = (off + bytes + 255) & ~(size_t)255;
        return p;
    };
    __half* Ah       = (__half*)alloc((size_t)n * 128 * 2);
    __half* h_node   = (__half*)alloc((size_t)n * 128 * 2);
    float*  a_s      = (float*)alloc((size_t)n * 4);
    float*  bd       = (float*)alloc((size_t)n * 4);
    int*    counts   = (int*)alloc((size_t)n * 4);
    int*    row_off  = (int*)alloc((size_t)(n + 1) * 4);
    int*    cursor   = (int*)alloc((size_t)n * 4);
    int*    partials = (int*)alloc(8192);
    float*  sc       = (float*)alloc(256);
    __half* Wc       = (__half*)alloc(64 * 128 * 2);
    float*  bc       = (float*)alloc(128 * 4);
    float4* recs     = (float4*)alloc((size_t)E * 16);

    int nb256 = (n + 255) / 256;
    int eb256 = (E + 255) / 256;
    int nscan = (n + 1023) / 1024;

    hipMemsetAsync(counts, 0, (size_t)n * 4, stream);
    k_hist<<<eb256, 256, 0, stream>>>(dst, counts, E);
    k_scan_a<<<nscan, 256, 0, stream>>>(counts, row_off, partials, n);
    k_scan_c<<<nb256, 256, 0, stream>>>(row_off, partials, cursor, n, E);
    k_prep<<<34, 256, 0, stream>>>(W2, b2, Wnm, bnm, attn, Wc, bc, sc);
    k_A<<<1024, 256, 0, stream>>>(feat, W1, b1, sc, Wc, bc, attn, Ah, a_s, bd, n, ntiles);
    k_fill<<<eb256, 256, 0, stream>>>(src, dst, bit, cursor, a_s, bd, sc, recs, E);
    k_node<<<n, 64, 0, stream>>>(feat, Wnm, bnm, Ah, row_off, recs, h_node);
    k_out<<<1024, 256, 0, stream>>>(h_node, Wo1, bo1, Wo2, bo2, out, n, ntiles);
}

// Round 20
// 366.628 us; speedup vs baseline: 1.4584x; 1.0332x over previous
//
#include <hip/hip_runtime.h>
#include <hip/hip_fp16.h>
#include <math.h>

// Decomposition:
//   t1 = lrelu(feat@W1+b1) (in-wave inside k_A)
//   A = t1 @ Wc + bc  (Wc=W2@Wnm_top: h only feeds A)
//   a_s = A@m; bd[v] = feat[v]@qb (fused into k_A)
//   w_e = exp(lrelu(a_s[src] + c1*bit + bd[dst] + c0, 0.2))  (fp32; no max)
//   neigh[v] = (sum w_e*A[src] + (sum w_e*bit)*wbit)/sum_w + B[v] + b_nm
//   out = mlp_out(relu(neigh))
// R1: same-address atomicAdd serializes -> block reduce.
// R6: fp16 A gather. R13: MFMA for dense matvecs.
// R7/R8/R14/R16: CSR fill = 1 random dirty 64B line/edge, ~90us flat floor.
// R17-R19: mid-tier is dispatch-count bound. k_t1/bd fused into k_A; scan_b
//     folded into scan_c.
// R20: two more independent-work merges: k_hp = hist+prep (block-partitioned);
//     k_Ac = scan_c + k_A (first 391 blocks scan, rest MFMA). 9->7 dispatches.

typedef _Float16 h2f __attribute__((ext_vector_type(2)));
typedef _Float16 h8  __attribute__((ext_vector_type(8)));
typedef float    f4  __attribute__((ext_vector_type(4)));

static __device__ __forceinline__ float lrelu(float x, float s) {
    return x >= 0.f ? x : s * x;
}

// ---------- k_hp: blk0 -> sc; blk1..33 -> Wc,bc; blk34.. -> dst histogram ----------
// sc[0]=c1=wbit@m  sc[1]=c0=b_nm@m  sc[2+k]=qb[k]=Wnm[129+k]@m
__global__ void __launch_bounds__(256) k_hp(const float* __restrict__ W2,
                                            const float* __restrict__ b2,
                                            const float* __restrict__ Wnm,
                                            const float* __restrict__ b_nm,
                                            const float* __restrict__ attn,
                                            __half* __restrict__ Wc,
                                            float* __restrict__ bc,
                                            float* __restrict__ sc,
                                            const int* __restrict__ dst,
                                            int* __restrict__ counts, int E) {
    int t = threadIdx.x;
    if (blockIdx.x == 0) {
        __shared__ float red[128];
        float m = (t < 128) ? attn[t] : 0.f;
        if (t < 128) red[t] = Wnm[128 * 128 + t] * m;
        __syncthreads();
        for (int s = 64; s > 0; s >>= 1) { if (t < s) red[t] += red[t + s]; __syncthreads(); }
        if (t == 0) sc[0] = red[0];
        __syncthreads();
        if (t < 128) red[t] = b_nm[t] * m;
        __syncthreads();
        for (int s = 64; s > 0; s >>= 1) { if (t < s) red[t] += red[t + s]; __syncthreads(); }
        if (t == 0) sc[1] = red[0];
        __syncthreads();
        for (int k = 0; k < 16; k++) {
            if (t < 128) red[t] = Wnm[(129 + k) * 128 + t] * m;
            __syncthreads();
            for (int s = 64; s > 0; s >>= 1) { if (t < s) red[t] += red[t + s]; __syncthreads(); }
            if (t == 0) sc[2 + k] = red[0];
            __syncthreads();
        }
    } else if (blockIdx.x <= 33) {
        int idx = (blockIdx.x - 1) * 256 + t;   // 65*128 outputs (row 64 = bias)
        if (idx >= 65 * 128) return;
        int j = idx >> 7, c = idx & 127;
        const float* row = (j < 64) ? &W2[j * 128] : b2;
        float acc = 0.f;
        for (int cp = 0; cp < 128; cp++) acc = fmaf(row[cp], Wnm[cp * 128 + c], acc);
        if (j < 64) Wc[j * 128 + c] = __float2half_rn(acc);
        else bc[c] = acc;
    } else {
        int e = (blockIdx.x - 34) * 256 + t;
        if (e < E) atomicAdd(&counts[dst[e]], 1);
    }
}

__global__ void k_scan_a(const int* counts, int* row_off, int* partials, int n) {
    __shared__ int sd[256];
    int t = threadIdx.x;
    int base = blockIdx.x * 1024 + t * 4;
    int v0 = (base + 0 < n) ? counts[base + 0] : 0;
    int v1 = (base + 1 < n) ? counts[base + 1] : 0;
    int v2 = (base + 2 < n) ? counts[base + 2] : 0;
    int v3 = (base + 3 < n) ? counts[base + 3] : 0;
    int s = v0 + v1 + v2 + v3;
    sd[t] = s; __syncthreads();
    for (int off = 1; off < 256; off <<= 1) {
        int x = (t >= off) ? sd[t - off] : 0;
        __syncthreads();
        sd[t] += x;
        __syncthreads();
    }
    int run = sd[t] - s;
    if (base + 0 < n) row_off[base + 0] = run; run += v0;
    if (base + 1 < n) row_off[base + 1] = run; run += v1;
    if (base + 2 < n) row_off[base + 2] = run; run += v2;
    if (base + 3 < n) row_off[base + 3] = run;
    if (t == 255) partials[blockIdx.x] = sd[255];
}

// ---------- k_Ac: blocks [0, nscan) -> scan_c fixup; blocks [nscan, ...) -> fused k_A
__global__ void __launch_bounds__(256) k_Ac(int* __restrict__ row_off,
                                            const int* __restrict__ partials,
                                            int* __restrict__ cursor,
                                            const float* __restrict__ feat,
                                            const float* __restrict__ W1,
                                            const float* __restrict__ b1,
                                            const float* __restrict__ sc,
                                            const __half* __restrict__ Wc,
                                            const float* __restrict__ bc,
                                            const float* __restrict__ attn,
                                            __half* __restrict__ Ah,
                                            float* __restrict__ a_s,
                                            float* __restrict__ bd,
                                            int n, int E, int ntiles,
                                            int nscan, int gridA) {
    __shared__ __half Wt[128 * 72];       // Wc^T: Wt[c][k], stride 72
    __shared__ float  W1s[16 * 64];
    __shared__ float  b1s[64];
    __shared__ __half t1s[4][16 * 72];
    int t = threadIdx.x;
    if ((int)blockIdx.x < nscan) {
        int i = blockIdx.x * 256 + t;
        if (i < n) {
            int g = i >> 10;
            int acc = 0;
            for (int j = 0; j < g; j++) acc += partials[j];
            int r = row_off[i] + acc;
            row_off[i] = r;
            cursor[i] = r;
        }
        if (i == 0) row_off[n] = E;
        return;
    }
    int bid = blockIdx.x - nscan;
    for (int idx = t; idx < 64 * 128; idx += 256) {
        int k = idx >> 7, c = idx & 127;
        Wt[c * 72 + k] = Wc[idx];
    }
    for (int idx = t; idx < 1024; idx += 256) W1s[idx] = W1[idx];
    if (t < 64) b1s[t] = b1[t];
    __syncthreads();
    int wave = t >> 6, lane = t & 63;
    int c = lane & 15, q = lane >> 4;
    float attv[8], bcv[8];
#pragma unroll
    for (int ct = 0; ct < 8; ct++) {
        attv[ct] = attn[ct * 16 + c];
        bcv[ct]  = bc[ct * 16 + c];
    }
    float qb[16];
#pragma unroll
    for (int k = 0; k < 16; k++) qb[k] = sc[2 + k];
    __half* myT1 = &t1s[wave][0];
    for (int tile = bid * 4 + wave; tile < ntiles; tile += gridA * 4) {
        int rowbase = tile * 16;
        int rm = min(rowbase + c, n - 1);
        const float4* fr = (const float4*)(feat + (size_t)rm * 16);
        float fv[16];
        *(float4*)&fv[0]  = fr[0];
        *(float4*)&fv[4]  = fr[1];
        *(float4*)&fv[8]  = fr[2];
        *(float4*)&fv[12] = fr[3];
        if (q == 0 && rowbase + c < n) {
            float bacc = 0.f;
#pragma unroll
            for (int k = 0; k < 16; k++) bacc = fmaf(fv[k], qb[k], bacc);
            bd[rowbase + c] = bacc;
        }
        {
            _Float16 tv[16];
#pragma unroll
            for (int jj = 0; jj < 16; jj++) {
                int j = q * 16 + jj;
                float acc = b1s[j];
#pragma unroll
                for (int k = 0; k < 16; k++) acc = fmaf(fv[k], W1s[k * 64 + j], acc);
                tv[jj] = (_Float16)lrelu(acc, 0.1f);
            }
            *(h8*)&myT1[c * 72 + q * 16 + 0] = *(h8*)&tv[0];
            *(h8*)&myT1[c * 72 + q * 16 + 8] = *(h8*)&tv[8];
        }
        h8 af[2];
#pragma unroll
        for (int ks = 0; ks < 2; ks++)
            af[ks] = *(const h8*)&myT1[c * 72 + ks * 32 + q * 8];
        f4 acc[8];
#pragma unroll
        for (int ct = 0; ct < 8; ct++) acc[ct] = (f4)(0.f);
#pragma unroll
        for (int ct = 0; ct < 8; ct++) {
#pragma unroll
            for (int ks = 0; ks < 2; ks++) {
                h8 bf = *(const h8*)&Wt[(ct * 16 + c) * 72 + ks * 32 + q * 8];
                acc[ct] = __builtin_amdgcn_mfma_f32_16x16x32_f16(af[ks], bf, acc[ct], 0, 0, 0);
            }
        }
        int rlim = n - rowbase;
        float s0 = 0.f, s1 = 0.f, s2 = 0.f, s3 = 0.f;
#pragma unroll
        for (int ct = 0; ct < 8; ct++) {
            int col = ct * 16 + c;
            float v0 = acc[ct][0] + bcv[ct];
            float v1 = acc[ct][1] + bcv[ct];
            float v2 = acc[ct][2] + bcv[ct];
            float v3 = acc[ct][3] + bcv[ct];
            if (q * 4 + 0 < rlim) Ah[(size_t)(rowbase + q * 4 + 0) * 128 + col] = __float2half_rn(v0);
            if (q * 4 + 1 < rlim) Ah[(size_t)(rowbase + q * 4 + 1) * 128 + col] = __float2half_rn(v1);
            if (q * 4 + 2 < rlim) Ah[(size_t)(rowbase + q * 4 + 2) * 128 + col] = __float2half_rn(v2);
            if (q * 4 + 3 < rlim) Ah[(size_t)(rowbase + q * 4 + 3) * 128 + col] = __float2half_rn(v3);
            s0 = fmaf(v0, attv[ct], s0);
            s1 = fmaf(v1, attv[ct], s1);
            s2 = fmaf(v2, attv[ct], s2);
            s3 = fmaf(v3, attv[ct], s3);
        }
#pragma unroll
        for (int off = 1; off < 16; off <<= 1) {
            s0 += __shfl_xor(s0, off, 64);
            s1 += __shfl_xor(s1, off, 64);
            s2 += __shfl_xor(s2, off, 64);
            s3 += __shfl_xor(s3, off, 64);
        }
        if (c == 0) {
            if (q * 4 + 0 < rlim) a_s[rowbase + q * 4 + 0] = s0;
            if (q * 4 + 1 < rlim) a_s[rowbase + q * 4 + 1] = s1;
            if (q * 4 + 2 < rlim) a_s[rowbase + q * 4 + 2] = s2;
            if (q * 4 + 3 < rlim) a_s[rowbase + q * 4 + 3] = s3;
        }
    }
}

// ---------- fill CSR: ONE 16B record {src, w, w*bit, pad} per edge (flat) ----------
__global__ void k_fill(const int* __restrict__ src, const int* __restrict__ dst,
                       const float* __restrict__ bit, int* __restrict__ cursor,
                       const float* __restrict__ a_s, const float* __restrict__ bd,
                       const float* __restrict__ sc, float4* __restrict__ recs, int E) {
    int e = blockIdx.x * blockDim.x + threadIdx.x;
    if (e >= E) return;
    int s = src[e], d = dst[e];
    float bv = bit[e];
    float logit = a_s[s] + sc[0] * bv + bd[d] + sc[1];
    float w = __expf(lrelu(logit, 0.2f));
    int p = atomicAdd(&cursor[d], 1);
    recs[p] = make_float4(__int_as_float(s), w, w * bv, 0.f);
}

// ---------- per-node aggregate -> h_node fp16; 64 thr, 2 ch/thread ----------
__global__ void __launch_bounds__(64, 4) k_node(const float* __restrict__ feat,
                                                const float* __restrict__ Wnm,
                                                const float* __restrict__ b_nm,
                                                const __half* __restrict__ Ah,
                                                const int* __restrict__ row_off,
                                                const float4* __restrict__ recs,
                                                __half* __restrict__ h_node) {
    int v = blockIdx.x;
    int t = threadIdx.x;
    int rs = row_off[v], re = row_off[v + 1];
    h2f* outp = (h2f*)&h_node[(size_t)v * 128 + 2 * t];
    const float4* fr = (const float4*)(feat + (size_t)v * 16);
    float fv[16];
    *(float4*)&fv[0]  = fr[0];
    *(float4*)&fv[4]  = fr[1];
    *(float4*)&fv[8]  = fr[2];
    *(float4*)&fv[12] = fr[3];
    float Bx = 0.f, By = 0.f;
#pragma unroll
    for (int k = 0; k < 16; k++) {
        float2 wr = *(const float2*)&Wnm[(129 + k) * 128 + 2 * t];
        Bx = fmaf(fv[k], wr.x, Bx);
        By = fmaf(fv[k], wr.y, By);
    }
    if (re == rs) { h2f z; z[0] = (_Float16)0.f; z[1] = (_Float16)0.f; *outp = z; return; }
    float ax = 0.f, ay = 0.f, sw = 0.f, swb = 0.f;
#pragma unroll 8
    for (int p = rs; p < re; ++p) {
        float4 rec = recs[p];
        int sv = __float_as_int(rec.x);
        float2 av = __half22float2(*(const __half2*)&Ah[(size_t)sv * 128 + 2 * t]);
        ax = fmaf(rec.y, av.x, ax);
        ay = fmaf(rec.y, av.y, ay);
        sw += rec.y;
        swb += rec.z;
    }
    float inv = 1.f / sw;
    float2 wb = *(const float2*)&Wnm[128 * 128 + 2 * t];
    float2 bn = *(const float2*)&b_nm[2 * t];
    float hx = fmaf(swb * inv, wb.x, ax * inv) + Bx + bn.x;
    float hy = fmaf(swb * inv, wb.y, ay * inv) + By + bn.y;
    h2f o; o[0] = (_Float16)fmaxf(hx, 0.f); o[1] = (_Float16)fmaxf(hy, 0.f);
    *outp = o;
}

// ---------- out = bo2 + sum_c lrelu(h_node@Wo1+bo1,0.1)[c]*Wo2[c], MFMA ----------
__global__ void __launch_bounds__(256) k_out(const __half* __restrict__ h_node,
                                             const float* __restrict__ Wo1,
                                             const float* __restrict__ bo1,
                                             const float* __restrict__ Wo2,
                                             const float* __restrict__ bo2,
                                             float* __restrict__ out,
                                             int n, int ntiles) {
    __shared__ __half Wt[128 * 136];
    int t = threadIdx.x;
    for (int idx = t; idx < 128 * 128; idx += 256) {
        int k = idx >> 7, c = idx & 127;
        Wt[c * 136 + k] = __float2half_rn(Wo1[idx]);
    }
    __syncthreads();
    int wave = t >> 6, lane = t & 63;
    int c = lane & 15, q = lane >> 4;
    float b1v[8], w2v[8];
#pragma unroll
    for (int ct = 0; ct < 8; ct++) {
        b1v[ct] = bo1[ct * 16 + c];
        w2v[ct] = Wo2[ct * 16 + c];
    }
    float bias2 = bo2[0];
    for (int tile = blockIdx.x * 4 + wave; tile < ntiles; tile += gridDim.x * 4) {
        int rowbase = tile * 16;
        int rm = min(rowbase + c, n - 1);
        h8 af[4];
#pragma unroll
        for (int ks = 0; ks < 4; ks++)
            af[ks] = *(const h8*)&h_node[(size_t)rm * 128 + ks * 32 + q * 8];
        f4 acc[8];
#pragma unroll
        for (int ct = 0; ct < 8; ct++) acc[ct] = (f4)(0.f);
#pragma unroll
        for (int ct = 0; ct < 8; ct++) {
#pragma unroll
            for (int ks = 0; ks < 4; ks++) {
                h8 bf = *(const h8*)&Wt[(ct * 16 + c) * 136 + ks * 32 + q * 8];
                acc[ct] = __builtin_amdgcn_mfma_f32_16x16x32_f16(af[ks], bf, acc[ct], 0, 0, 0);
            }
        }
        int rlim = n - rowbase;
        float s0 = 0.f, s1 = 0.f, s2 = 0.f, s3 = 0.f;
#pragma unroll
        for (int ct = 0; ct < 8; ct++) {
            s0 = fmaf(lrelu(acc[ct][0] + b1v[ct], 0.1f), w2v[ct], s0);
            s1 = fmaf(lrelu(acc[ct][1] + b1v[ct], 0.1f), w2v[ct], s1);
            s2 = fmaf(lrelu(acc[ct][2] + b1v[ct], 0.1f), w2v[ct], s2);
            s3 = fmaf(lrelu(acc[ct][3] + b1v[ct], 0.1f), w2v[ct], s3);
        }
#pragma unroll
        for (int off = 1; off < 16; off <<= 1) {
            s0 += __shfl_xor(s0, off, 64);
            s1 += __shfl_xor(s1, off, 64);
            s2 += __shfl_xor(s2, off, 64);
            s3 += __shfl_xor(s3, off, 64);
        }
        if (c == 0) {
            if (q * 4 + 0 < rlim) out[rowbase + q * 4 + 0] = bias2 + s0;
            if (q * 4 + 1 < rlim) out[rowbase + q * 4 + 1] = bias2 + s1;
            if (q * 4 + 2 < rlim) out[rowbase + q * 4 + 2] = bias2 + s2;
            if (q * 4 + 3 < rlim) out[rowbase + q * 4 + 3] = bias2 + s3;
        }
    }
}

extern "C" void kernel_launch(void* const* d_in, const int* in_sizes, int n_in,
                              void* d_out, int out_size, void* d_ws, size_t ws_size,
                              hipStream_t stream) {
    const float* feat = (const float*)d_in[0];
    const float* bit  = (const float*)d_in[1];
    const int*   src  = (const int*)d_in[2];
    const int*   dst  = (const int*)d_in[3];
    const float* W1   = (const float*)d_in[4];
    const float* b1   = (const float*)d_in[5];
    const float* W2   = (const float*)d_in[6];
    const float* b2   = (const float*)d_in[7];
    const float* Wnm  = (const float*)d_in[8];
    const float* bnm  = (const float*)d_in[9];
    const float* attn = (const float*)d_in[10];
    const float* Wo1  = (const float*)d_in[11];
    const float* bo1  = (const float*)d_in[12];
    const float* Wo2  = (const float*)d_in[13];
    const float* bo2  = (const float*)d_in[14];
    float* out = (float*)d_out;
    int n = in_sizes[0] / 16;
    int E = in_sizes[2];
    int ntiles = (n + 15) / 16;

    char* wsp = (char*)d_ws;
    size_t off = 0;
    auto alloc = [&](size_t bytes) -> void* {
        void* p = wsp + off;
        off = (off + bytes + 255) & ~(size_t)255;
        return p;
    };
    __half* Ah       = (__half*)alloc((size_t)n * 128 * 2);
    __half* h_node   = (__half*)alloc((size_t)n * 128 * 2);
    float*  a_s      = (float*)alloc((size_t)n * 4);
    float*  bd       = (float*)alloc((size_t)n * 4);
    int*    counts   = (int*)alloc((size_t)n * 4);
    int*    row_off  = (int*)alloc((size_t)(n + 1) * 4);
    int*    cursor   = (int*)alloc((size_t)n * 4);
    int*    partials = (int*)alloc(8192);
    float*  sc       = (float*)alloc(256);
    __half* Wc       = (__half*)alloc(64 * 128 * 2);
    float*  bc       = (float*)alloc(128 * 4);
    float4* recs     = (float4*)alloc((size_t)E * 16);

    int nb256 = (n + 255) / 256;
    int eb256 = (E + 255) / 256;
    int nscan = (n + 1023) / 1024;
    int gridA = 1024;

    hipMemsetAsync(counts, 0, (size_t)n * 4, stream);
    k_hp<<<34 + eb256, 256, 0, stream>>>(W2, b2, Wnm, bnm, attn, Wc, bc, sc,
                                         dst, counts, E);
    k_scan_a<<<nscan, 256, 0, stream>>>(counts, row_off, partials, n);
    k_Ac<<<nb256 + gridA, 256, 0, stream>>>(row_off, partials, cursor,
                                            feat, W1, b1, sc, Wc, bc, attn,
                                            Ah, a_s, bd, n, E, ntiles, nb256, gridA);
    k_fill<<<eb256, 256, 0, stream>>>(src, dst, bit, cursor, a_s, bd, sc, recs, E);
    k_node<<<n, 64, 0, stream>>>(feat, Wnm, bnm, Ah, row_off, recs, h_node);
    k_out<<<1024, 256, 0, stream>>>(h_node, Wo1, bo1, Wo2, bo2, out, n, ntiles);
}